// Round 9
// baseline (499.916 us; speedup 1.0000x reference)
//
#include <hip/hip_runtime.h>

#define DEG 16
#define DD  128
#define KT  10      // template nodes (K)
#define TT  10      // templates
#define MM  17      // m = DEG+1
#define NPB 4       // nodes per block
#define THREADS 640 // 10 waves: wave w <-> template w

#if __has_builtin(__builtin_amdgcn_exp2f)
#define FEXP2(x) __builtin_amdgcn_exp2f(x)
#else
#define FEXP2(x) exp2f(x)
#endif

#if __has_builtin(__builtin_amdgcn_rcpf)
#define FRCP(x) __builtin_amdgcn_rcpf(x)
#else
#define FRCP(x) (1.0f / (x))
#endif

#if __has_builtin(__builtin_amdgcn_logf)
#define FLOG2(x) __builtin_amdgcn_logf(x)
#else
#define FLOG2(x) __log2f(x)
#endif

// (1/EPS)*log2(e), EPS = 0.5
#define TWO_LOG2E 2.8853900817779268f
// log2(e): scale for the hoisted exp2 of 0.5*Mc
#define NLOG2E    1.4426950408889634f
// EPS*ln2 = 1/TWO_LOG2E: recovers 0.5*Mc from log2(eM)
#define EPSLN2    0.34657359027997264f
// QP = qw/pw = 17/10 folded into the 2-wide u-update: RQP = 1/QP = 10/17
#define RQP       0.5882352941176471f
// vv'' initial value = 1/QP
#define VV0       0.5882352941176471f
// pw*QP = (1/17)*(17/10) = 1/10 exactly
#define PWQP      0.1f

typedef float v2f __attribute__((ext_vector_type(2)));
typedef float v4f __attribute__((ext_vector_type(4)));

// packed fp32 fma, both mul operands in VGPRs
__device__ __forceinline__ v2f pk_fma(v2f a, v2f b, v2f c) {
    asm("v_pk_fma_f32 %0, %1, %2, %0" : "+v"(c) : "v"(a), "v"(b));
    return c;
}
// packed fp32 fma with a wave-uniform operand pinned to an SGPR pair:
// template data stays in scalar registers (s_load), offloading the VALU.
__device__ __forceinline__ v2f pk_fma_s(v2f a, v2f bs, v2f c) {
    asm("v_pk_fma_f32 %0, %1, %2, %0" : "+v"(c) : "v"(a), "s"(bs));
    return c;
}

// builtin-based 16-lane sum for the final objective
template <int CTRL>
__device__ __forceinline__ float dpp_add(float x) {
    union { float f; int i; } a, b;
    a.f = x;
    b.i = __builtin_amdgcn_update_dpp(0, a.i, CTRL, 0xF, 0xF, true);
    return x + b.f;
}
__device__ __forceinline__ float sum16(float t) {
    t = dpp_add<0xB1>(t);
    t = dpp_add<0x4E>(t);
    t = dpp_add<0x124>(t);
    t = dpp_add<0x128>(t);
    return t;
}

// hand-fused multi-value 16-lane butterflies (v_add_f32_dpp).
// VALU->DPP hazard needs 2 wait states: entry s_nop 1; interior spacing >=4.
#define _D(i, CTRL) "v_add_f32_dpp %" #i ", %" #i ", %" #i " " CTRL \
                    " row_mask:0xf bank_mask:0xf bound_ctrl:0\n\t"
#define _C1 "quad_perm:[1,0,3,2]"
#define _C2 "quad_perm:[2,3,0,1]"
#define _C3 "row_ror:4"
#define _C4 "row_ror:8"

__device__ __forceinline__ void sum16x6(float& a0, float& a1, float& a2,
                                        float& a3, float& a4, float& a5) {
    asm("s_nop 1\n\t"
        _D(0,_C1) _D(1,_C1) _D(2,_C1) _D(3,_C1) _D(4,_C1) _D(5,_C1)
        _D(0,_C2) _D(1,_C2) _D(2,_C2) _D(3,_C2) _D(4,_C2) _D(5,_C2)
        _D(0,_C3) _D(1,_C3) _D(2,_C3) _D(3,_C3) _D(4,_C3) _D(5,_C3)
        _D(0,_C4) _D(1,_C4) _D(2,_C4) _D(3,_C4) _D(4,_C4) _D(5,_C4)
        : "+v"(a0), "+v"(a1), "+v"(a2), "+v"(a3), "+v"(a4), "+v"(a5));
}

__device__ __forceinline__ void sum16x5(float& a0, float& a1, float& a2,
                                        float& a3, float& a4) {
    asm("s_nop 1\n\t"
        _D(0,_C1) _D(1,_C1) _D(2,_C1) _D(3,_C1) _D(4,_C1)
        _D(0,_C2) _D(1,_C2) _D(2,_C2) _D(3,_C2) _D(4,_C2)
        _D(0,_C3) _D(1,_C3) _D(2,_C3) _D(3,_C3) _D(4,_C3)
        _D(0,_C4) _D(1,_C4) _D(2,_C4) _D(3,_C4) _D(4,_C4)
        : "+v"(a0), "+v"(a1), "+v"(a2), "+v"(a3), "+v"(a4));
}

// Layout: wave w <-> template w; 64 lanes = 4 node-slots (p) x 16 lanes.
// Lane l owns neighbor row jn = l (graph row j = l+1); center row j=0 is
// x[node] itself, read coalesced from global in the mini-pass.
// LDS = 4 nodes x 16 rows x 128 floats = 32768 B.
//
// R9: bit-exact EARLY EXIT in the Sinkhorn inner loop. The reference runs a
// fixed 10 iterations; with EPS=0.5 the fp32 fixed point is typically reached
// in 3-7. Once u is bitwise stationary, vv = f(u) and u' = g(vv) are pure
// deterministic functions, so all remaining iterations are bit-identical
// no-ops -- skipping them cannot change the output by even 1 ulp.
__global__ __launch_bounds__(THREADS, 4) void ltfgw_kernel(
    const float* __restrict__ x,      // [N,128]
    const int*   __restrict__ ei,     // edge_index[0], [N*DEG]
    const float* __restrict__ tmpl,   // [T,K,K]
    const float* __restrict__ tf,     // [T,K,128]
    float* __restrict__ out,          // [N,T]
    int N)
{
    __shared__ float sFi[NPB * DEG * DD];   // 32768 B exactly

    const int tid = threadIdx.x;
    const int b0  = blockIdx.x * NPB;

    // ---- stage neighbor rows (center row j=0 comes from global later)
    {
        const int kq = tid & 31;
        for (int r = tid >> 5; r < NPB * DEG; r += (THREADS >> 5)) {
            int p = r >> 4, jn = r & 15;
            int node = b0 + p;
            if (node < N) {
                int src = ei[node * DEG + jn];
                float4 v4 = *(const float4*)(x + (size_t)src * DD + kq * 4);
                *(float4*)(&sFi[(p << 11) + (jn << 7) + ((kq ^ (jn & 7)) << 2)]) = v4;
            }
        }
    }
    __syncthreads();

    const int w     = tid >> 6;
    const int wu    = __builtin_amdgcn_readfirstlane(w);
    const int lane  = tid & 63;
    const int p     = lane >> 4;
    const int l     = lane & 15;
    const int gbase = lane & ~15;
    const int node  = b0 + p;
    const int nodeC = (node < N) ? node : (N - 1);   // clamp for reads

    const int cl = (l < KT) ? l : 0;
    // Ct row base for column cl (8B-aligned: 40-byte row stride)
    const float* ctp = tmpl + ((size_t)wu * KT + cl) * KT;

    // ---- ct2q = (Ct^2 @ q)[cl]
    float ct2q;
    {
        v2f r0 = *(const v2f*)(ctp);
        v2f r1 = *(const v2f*)(ctp + 2);
        v2f r2 = *(const v2f*)(ctp + 4);
        v2f r3 = *(const v2f*)(ctp + 6);
        v2f r4 = *(const v2f*)(ctp + 8);
        v2f acc = pk_fma(r0, r0, (v2f){0.f, 0.f});
        acc = pk_fma(r1, r1, acc);
        acc = pk_fma(r2, r2, acc);
        acc = pk_fma(r3, r3, acc);
        acc = pk_fma(r4, r4, acc);
        ct2q = (acc.x + acc.y) * (1.f / KT);
    }

    // ---- M main pass: own neighbor row (LDS, swizzled) vs 10 template rows
    // (wave-uniform addresses -> s_load, SGPR operands)
    const int rowbase = (p << 11) + (l << 7);
    const int swz     = l & 7;
    const float* tw   = tf + (size_t)wu * KT * DD;   // wave-uniform
    v2f dotv[KT];
#pragma unroll
    for (int c = 0; c < KT; ++c) dotv[c] = (v2f){0.f, 0.f};
    v2f nrmv = (v2f){0.f, 0.f};
#pragma unroll 4
    for (int kk4 = 0; kk4 < 32; ++kk4) {
        v4f a4 = *(const v4f*)(&sFi[rowbase + ((kk4 ^ swz) << 2)]);
        nrmv = pk_fma(a4.lo, a4.lo, nrmv);
        nrmv = pk_fma(a4.hi, a4.hi, nrmv);
#pragma unroll
        for (int c = 0; c < KT; ++c) {
            v4f f4 = *(const v4f*)(tw + c * DD + kk4 * 4);   // uniform -> s_load
            dotv[c] = pk_fma_s(a4.lo, f4.lo, dotv[c]);
            dotv[c] = pk_fma_s(a4.hi, f4.hi, dotv[c]);
        }
    }
    float nrm_own = nrmv.x + nrmv.y;

    // ---- mini-pass: center row (from GLOBAL, coalesced 32B/lane) dots +
    // template norms + row0 norm (k-distributed: lane l covers [8l, 8l+8))
    float dot0[KT], nft[KT], n0p;
    {
        const float* row0 = x + (size_t)nodeC * DD + 8 * l;
        v4f z0 = *(const v4f*)(row0);
        v4f z1 = *(const v4f*)(row0 + 4);
        v2f nn = pk_fma(z0.lo, z0.lo, (v2f){0.f, 0.f});
        nn = pk_fma(z0.hi, z0.hi, nn);
        nn = pk_fma(z1.lo, z1.lo, nn);
        nn = pk_fma(z1.hi, z1.hi, nn);
        n0p = nn.x + nn.y;
#pragma unroll
        for (int c = 0; c < KT; ++c) {
            const float* tr = tw + c * DD + 8 * l;   // coalesced across lanes
            v4f t0_ = *(const v4f*)(tr);
            v4f t1_ = *(const v4f*)(tr + 4);
            v2f d = pk_fma(z0.lo, t0_.lo, (v2f){0.f, 0.f});
            d = pk_fma(z0.hi, t0_.hi, d);
            d = pk_fma(z1.lo, t1_.lo, d);
            d = pk_fma(z1.hi, t1_.hi, d);
            dot0[c] = d.x + d.y;
            v2f nf = pk_fma(t0_.lo, t0_.lo, (v2f){0.f, 0.f});
            nf = pk_fma(t0_.hi, t0_.hi, nf);
            nf = pk_fma(t1_.lo, t1_.lo, nf);
            nf = pk_fma(t1_.hi, t1_.hi, nf);
            nft[c] = nf.x + nf.y;
        }
        sum16x6(dot0[0], dot0[1], dot0[2], dot0[3], dot0[4], dot0[5]);
        sum16x5(dot0[6], dot0[7], dot0[8], dot0[9], n0p);
        sum16x5(nft[0], nft[1], nft[2], nft[3], nft[4]);
        sum16x5(nft[5], nft[6], nft[7], nft[8], nft[9]);
    }

    // ---- hoisted mirror factors eM = exp2(-log2e * Mc)
    float eM_own[KT], eM0[KT];
#pragma unroll
    for (int c = 0; c < KT; ++c) {
        float mc0 = (n0p + nft[c] - 2.f * dot0[c]) * (1.f / DD);
        eM0[c] = FEXP2(-NLOG2E * mc0);
        float mcw = (nrm_own + nft[c] - 2.f * (dotv[c].x + dotv[c].y)) * (1.f / DD);
        eM_own[c] = FEXP2(-NLOG2E * mcw);
    }

    // ---- proximal Sinkhorn. TKo/TK0 hold Tp at outer boundaries, eK inside.
    float TKo[KT], TK0[KT], vv[KT];
#pragma unroll
    for (int c = 0; c < KT; ++c) {
        TKo[c] = 1.f / (MM * KT);
        TK0[c] = 1.f / (MM * KT);
    }
    float u_own = 0.f, u0 = 0.f;

#pragma unroll 1
    for (int outer = 0; outer < 5; ++outer) {
        // s[c] = 16-lane sum of Tp over neighbor rows
        float s[KT];
#pragma unroll
        for (int c = 0; c < KT; ++c) s[c] = TKo[c];
        sum16x5(s[0], s[1], s[2], s[3], s[4]);
        sum16x5(s[5], s[6], s[7], s[8], s[9]);

        // Ct row reload (L1-resident, 5x8B) + distributed Cs/C0 on column cl
        v2f r0 = *(const v2f*)(ctp);
        v2f r1 = *(const v2f*)(ctp + 2);
        v2f r2 = *(const v2f*)(ctp + 4);
        v2f r3 = *(const v2f*)(ctp + 6);
        v2f r4 = *(const v2f*)(ctp + 8);
        float Cs, C0;
        {
            float a = r0.x * s[0],   b = r0.y * s[1];
            a = fmaf(r1.x, s[2], a); b = fmaf(r1.y, s[3], b);
            a = fmaf(r2.x, s[4], a); b = fmaf(r2.y, s[5], b);
            a = fmaf(r3.x, s[6], a); b = fmaf(r3.y, s[7], b);
            a = fmaf(r4.x, s[8], a); b = fmaf(r4.y, s[9], b);
            Cs = a + b;
            float q = r0.x * TK0[0],   d = r0.y * TK0[1];
            q = fmaf(r1.x, TK0[2], q); d = fmaf(r1.y, TK0[3], d);
            q = fmaf(r2.x, TK0[4], q); d = fmaf(r2.y, TK0[5], d);
            q = fmaf(r3.x, TK0[6], q); d = fmaf(r3.y, TK0[7], d);
            q = fmaf(r4.x, TK0[8], q); d = fmaf(r4.y, TK0[9], d);
            C0 = q + d;
        }
        float e0 = FEXP2(-TWO_LOG2E * ((16.f / 17.f) + ct2q - 2.f * Cs));
        float e1 = FEXP2(-TWO_LOG2E * ((1.f  / 17.f) + ct2q - 2.f * C0));

        // Tp -> eK in place
#pragma unroll
        for (int c = 0; c < KT; ++c) {
            float E1c = __shfl(e1, gbase + c, 64);
            TKo[c] = TKo[c] * (eM_own[c] * E1c);
            float E0c = __shfl(e0, gbase + c, 64);
            TK0[c] = TK0[c] * (eM0[c] * E0c);
            vv[c] = VV0;   // vv'' = vv/QP
        }

        // <=10 Sinkhorn iterations with bit-exact early exit:
        //   u = RQP * rcp(sum_c eK*vv'');  vv'' = rcp(sum_rows eK*u)
        // Exit when u is bitwise stationary on ALL 64 lanes: vv and all
        // further iterates are then deterministically identical, so the
        // skipped iterations are exact no-ops (output unchanged to the ulp).
        unsigned puo = 0xFFFFFFFFu, pu0b = 0xFFFFFFFFu;
#pragma unroll 1
        for (int it = 0; it < 10; ++it) {
            float ra = TKo[0] * vv[0], rb = TKo[1] * vv[1];
            float qa = TK0[0] * vv[0], qb = TK0[1] * vv[1];
#pragma unroll
            for (int c = 2; c < KT; c += 2) {
                ra = fmaf(TKo[c],     vv[c],     ra);
                rb = fmaf(TKo[c + 1], vv[c + 1], rb);
                qa = fmaf(TK0[c],     vv[c],     qa);
                qb = fmaf(TK0[c + 1], vv[c + 1], qb);
            }
            u_own = RQP * FRCP(ra + rb);
            u0    = RQP * FRCP(qa + qb);
            // convergence check BEFORE the butterfly/vv recompute: if u is
            // stationary, the vv from the previous iteration is bitwise what
            // this iteration would produce.
            unsigned bu = __float_as_uint(u_own);
            unsigned b0c = __float_as_uint(u0);
            bool conv = (bu == puo) && (b0c == pu0b);
            puo = bu; pu0b = b0c;
            if (__all(conv)) break;
            float t[KT];
#pragma unroll
            for (int c = 0; c < KT; ++c) t[c] = TKo[c] * u_own;
            sum16x5(t[0], t[1], t[2], t[3], t[4]);
            sum16x5(t[5], t[6], t[7], t[8], t[9]);
#pragma unroll
            for (int c = 0; c < KT; ++c)
                vv[c] = FRCP(fmaf(TK0[c], u0, t[c]));
        }

        // eK -> Tp in place: Tp = (pw*QP) * u * eK * vv''
        float puw = PWQP * u_own, pu0 = PWQP * u0;
#pragma unroll
        for (int c = 0; c < KT; ++c) {
            TKo[c] = (TKo[c] * vv[c]) * puw;
            TK0[c] = (TK0[c] * vv[c]) * pu0;
        }
    }

    // ---- final objective from converged Tp
    float obj;
    {
        float s[KT];
#pragma unroll
        for (int c = 0; c < KT; ++c) s[c] = TKo[c];
        sum16x5(s[0], s[1], s[2], s[3], s[4]);
        sum16x5(s[5], s[6], s[7], s[8], s[9]);
        v2f r0 = *(const v2f*)(ctp);
        v2f r1 = *(const v2f*)(ctp + 2);
        v2f r2 = *(const v2f*)(ctp + 4);
        v2f r3 = *(const v2f*)(ctp + 6);
        v2f r4 = *(const v2f*)(ctp + 8);
        float Cs, C0;
        {
            float a = r0.x * s[0],   b = r0.y * s[1];
            a = fmaf(r1.x, s[2], a); b = fmaf(r1.y, s[3], b);
            a = fmaf(r2.x, s[4], a); b = fmaf(r2.y, s[5], b);
            a = fmaf(r3.x, s[6], a); b = fmaf(r3.y, s[7], b);
            a = fmaf(r4.x, s[8], a); b = fmaf(r4.y, s[9], b);
            Cs = a + b;
            float q = r0.x * TK0[0],   d = r0.y * TK0[1];
            q = fmaf(r1.x, TK0[2], q); d = fmaf(r1.y, TK0[3], d);
            q = fmaf(r2.x, TK0[4], q); d = fmaf(r2.y, TK0[5], d);
            q = fmaf(r3.x, TK0[6], q); d = fmaf(r3.y, TK0[7], d);
            q = fmaf(r4.x, TK0[8], q); d = fmaf(r4.y, TK0[9], d);
            C0 = q + d;
        }
        float g0l = (16.f / 17.f) + ct2q - 2.f * Cs;
        float g1l = (1.f  / 17.f) + ct2q - 2.f * C0;
        float obj_own = 0.f, obj0 = 0.f;
#pragma unroll
        for (int c = 0; c < KT; ++c) {
            float G1c = __shfl(g1l, gbase + c, 64);
            float hM  = -EPSLN2 * FLOG2(eM_own[c]);    // == 0.5*Mc_own[c]
            obj_own += TKo[c] * (hM + 0.5f * G1c);
            float G0c = __shfl(g0l, gbase + c, 64);
            float hM0 = -EPSLN2 * FLOG2(eM0[c]);       // == 0.5*Mc0[c]
            obj0 += TK0[c] * (hM0 + 0.5f * G0c);
        }
        obj = sum16(obj_own) + obj0;
    }

    if (l == 0 && node < N) out[node * TT + w] = obj;
}

extern "C" void kernel_launch(void* const* d_in, const int* in_sizes, int n_in,
                              void* d_out, int out_size, void* d_ws, size_t ws_size,
                              hipStream_t stream) {
    const float* x    = (const float*)d_in[0];
    const int*   ei   = (const int*)d_in[1];
    const float* tmpl = (const float*)d_in[2];
    const float* tf   = (const float*)d_in[3];
    float* out = (float*)d_out;
    int N = in_sizes[0] / DD;
    int grid = (N + NPB - 1) / NPB;
    hipLaunchKernelGGL(ltfgw_kernel, dim3(grid), dim3(THREADS), 0, stream,
                       x, ei, tmpl, tf, out, N);
}

// Round 10
// 371.429 us; speedup vs baseline: 1.3459x; 1.3459x over previous
//
#include <hip/hip_runtime.h>

#define DEG 16
#define DD  128
#define KT  10      // template nodes (K)
#define TT  10      // templates
#define MM  17      // m = DEG+1
#define NPB 4       // nodes per block
#define THREADS 640 // 10 waves: wave w <-> template w

#if __has_builtin(__builtin_amdgcn_exp2f)
#define FEXP2(x) __builtin_amdgcn_exp2f(x)
#else
#define FEXP2(x) exp2f(x)
#endif

#if __has_builtin(__builtin_amdgcn_rcpf)
#define FRCP(x) __builtin_amdgcn_rcpf(x)
#else
#define FRCP(x) (1.0f / (x))
#endif

#if __has_builtin(__builtin_amdgcn_logf)
#define FLOG2(x) __builtin_amdgcn_logf(x)
#else
#define FLOG2(x) __log2f(x)
#endif

// (1/EPS)*log2(e), EPS = 0.5
#define TWO_LOG2E 2.8853900817779268f
// log2(e): scale for the hoisted exp2 of 0.5*Mc
#define NLOG2E    1.4426950408889634f
// EPS*ln2 = 1/TWO_LOG2E: recovers 0.5*Mc from log2(eM)
#define EPSLN2    0.34657359027997264f
// QP = qw/pw = 17/10 folded into the u-update: RQP = 1/QP = 10/17
#define RQP       0.5882352941176471f
// vv'' initial value = 1/QP
#define VV0       0.5882352941176471f
// pw*QP = (1/17)*(17/10) = 1/10 exactly
#define PWQP      0.1f

typedef float v2f __attribute__((ext_vector_type(2)));
typedef float v4f __attribute__((ext_vector_type(4)));

// packed fp32 fma, both mul operands in VGPRs
__device__ __forceinline__ v2f pk_fma(v2f a, v2f b, v2f c) {
    asm("v_pk_fma_f32 %0, %1, %2, %0" : "+v"(c) : "v"(a), "v"(b));
    return c;
}
// packed fp32 fma with a wave-uniform operand pinned to an SGPR pair
__device__ __forceinline__ v2f pk_fma_s(v2f a, v2f bs, v2f c) {
    asm("v_pk_fma_f32 %0, %1, %2, %0" : "+v"(c) : "v"(a), "s"(bs));
    return c;
}

// builtin-based 16-lane sum for the final objective
template <int CTRL>
__device__ __forceinline__ float dpp_add(float x) {
    union { float f; int i; } a, b;
    a.f = x;
    b.i = __builtin_amdgcn_update_dpp(0, a.i, CTRL, 0xF, 0xF, true);
    return x + b.f;
}
__device__ __forceinline__ float sum16(float t) {
    t = dpp_add<0xB1>(t);
    t = dpp_add<0x4E>(t);
    t = dpp_add<0x124>(t);
    t = dpp_add<0x128>(t);
    return t;
}

// hand-fused multi-value butterflies (v_add_f32_dpp).
// VALU->DPP hazard = 2 wait states: entry s_nop 1; interior spacing kept >=2
// (sumq3 adds an s_nop 0 to be safe at width 3).
#define _D(i, CTRL) "v_add_f32_dpp %" #i ", %" #i ", %" #i " " CTRL \
                    " row_mask:0xf bank_mask:0xf bound_ctrl:0\n\t"
#define _C1 "quad_perm:[1,0,3,2]"
#define _C2 "quad_perm:[2,3,0,1]"
#define _C3 "row_ror:4"
#define _C4 "row_ror:8"

// full 16-sum of 5 values (used by the 1D mini-pass reductions)
__device__ __forceinline__ void sum16x5(float& a0, float& a1, float& a2,
                                        float& a3, float& a4) {
    asm("s_nop 1\n\t"
        _D(0,_C1) _D(1,_C1) _D(2,_C1) _D(3,_C1) _D(4,_C1)
        _D(0,_C2) _D(1,_C2) _D(2,_C2) _D(3,_C2) _D(4,_C2)
        _D(0,_C3) _D(1,_C3) _D(2,_C3) _D(3,_C3) _D(4,_C3)
        _D(0,_C4) _D(1,_C4) _D(2,_C4) _D(3,_C4) _D(4,_C4)
        : "+v"(a0), "+v"(a1), "+v"(a2), "+v"(a3), "+v"(a4));
}
__device__ __forceinline__ void sum16x6(float& a0, float& a1, float& a2,
                                        float& a3, float& a4, float& a5) {
    asm("s_nop 1\n\t"
        _D(0,_C1) _D(1,_C1) _D(2,_C1) _D(3,_C1) _D(4,_C1) _D(5,_C1)
        _D(0,_C2) _D(1,_C2) _D(2,_C2) _D(3,_C2) _D(4,_C2) _D(5,_C2)
        _D(0,_C3) _D(1,_C3) _D(2,_C3) _D(3,_C3) _D(4,_C3) _D(5,_C3)
        _D(0,_C4) _D(1,_C4) _D(2,_C4) _D(3,_C4) _D(4,_C4) _D(5,_C4)
        : "+v"(a0), "+v"(a1), "+v"(a2), "+v"(a3), "+v"(a4), "+v"(a5));
}

// sum over the quad (lanes 4k..4k+3, i.e. over rg), result broadcast in quad
__device__ __forceinline__ void sumq3(float& a0, float& a1, float& a2) {
    asm("s_nop 1\n\t"
        _D(0,_C1) _D(1,_C1) _D(2,_C1)
        "s_nop 0\n\t"
        _D(0,_C2) _D(1,_C2) _D(2,_C2)
        : "+v"(a0), "+v"(a1), "+v"(a2));
}
// sum over stride-4 lanes {l, l+4, l+8, l+12} (i.e. over cg), broadcast
__device__ __forceinline__ void sums5(float& a0, float& a1, float& a2,
                                      float& a3, float& a4) {
    asm("s_nop 1\n\t"
        _D(0,_C3) _D(1,_C3) _D(2,_C3) _D(3,_C3) _D(4,_C3)
        _D(0,_C4) _D(1,_C4) _D(2,_C4) _D(3,_C4) _D(4,_C4)
        : "+v"(a0), "+v"(a1), "+v"(a2), "+v"(a3), "+v"(a4));
}

// Layout: wave w <-> template w; 64 lanes = 4 node-slots (p) x 16 lanes.
// M-phase (1D): lane l owns neighbor row j=l+1 (as R8). Sinkhorn (2D):
// lane = (rg,cg) = (l&3, l>>2); owns neighbor rows {rg,rg+4,rg+8,rg+12} x
// cols {cbase..cbase+2} (10 cols split 3/3/2/2 + inert dummy for cg>=2);
// row 0 column-distributed. Row sums: 3-fma + 2-DPP (ror4/8 over cg).
// Col sums: 4-fma + 2-DPP (quad over rg). rcp/iter 12 -> 8, DPP 40 -> 16.
// eM crosses 1D->2D via an LDS overlay on the dead sFi buffer.
__global__ __launch_bounds__(THREADS, 4) void ltfgw_kernel(
    const float* __restrict__ x,      // [N,128]
    const int*   __restrict__ ei,     // edge_index[0], [N*DEG]
    const float* __restrict__ tmpl,   // [T,K,K]
    const float* __restrict__ tf,     // [T,K,128]
    float* __restrict__ out,          // [N,T]
    int N)
{
    __shared__ float sFi[NPB * DEG * DD];   // 32768 B; overlay eM[w][p][17][10]

    const int tid = threadIdx.x;
    const int b0  = blockIdx.x * NPB;

    // ---- stage neighbor rows (center row j=0 read from global later)
    {
        const int kq = tid & 31;
        for (int r = tid >> 5; r < NPB * DEG; r += (THREADS >> 5)) {
            int p = r >> 4, jn = r & 15;
            int node = b0 + p;
            if (node < N) {
                int src = ei[node * DEG + jn];
                float4 v4 = *(const float4*)(x + (size_t)src * DD + kq * 4);
                *(float4*)(&sFi[(p << 11) + (jn << 7) + ((kq ^ (jn & 7)) << 2)]) = v4;
            }
        }
    }
    __syncthreads();

    const int w     = tid >> 6;
    const int wu    = __builtin_amdgcn_readfirstlane(w);
    const int lane  = tid & 63;
    const int p     = lane >> 4;
    const int l     = lane & 15;
    const int gbase = lane & ~15;
    const int node  = b0 + p;
    const int nodeC = (node < N) ? node : (N - 1);

    const int cl = (l < KT) ? l : 0;
    const float* ctp = tmpl + ((size_t)wu * KT + cl) * KT;

    // ---- ct2q = (Ct^2 @ q)[cl]
    float ct2q;
    {
        v2f r0 = *(const v2f*)(ctp);
        v2f r1 = *(const v2f*)(ctp + 2);
        v2f r2 = *(const v2f*)(ctp + 4);
        v2f r3 = *(const v2f*)(ctp + 6);
        v2f r4 = *(const v2f*)(ctp + 8);
        v2f acc = pk_fma(r0, r0, (v2f){0.f, 0.f});
        acc = pk_fma(r1, r1, acc);
        acc = pk_fma(r2, r2, acc);
        acc = pk_fma(r3, r3, acc);
        acc = pk_fma(r4, r4, acc);
        ct2q = (acc.x + acc.y) * (1.f / KT);
    }

    // ---- M main pass (1D): own neighbor row (LDS, swizzled) vs 10 templates
    const int rowbase = (p << 11) + (l << 7);
    const int swz     = l & 7;
    const float* tw   = tf + (size_t)wu * KT * DD;
    v2f dotv[KT];
#pragma unroll
    for (int c = 0; c < KT; ++c) dotv[c] = (v2f){0.f, 0.f};
    v2f nrmv = (v2f){0.f, 0.f};
#pragma unroll 4
    for (int kk4 = 0; kk4 < 32; ++kk4) {
        v4f a4 = *(const v4f*)(&sFi[rowbase + ((kk4 ^ swz) << 2)]);
        nrmv = pk_fma(a4.lo, a4.lo, nrmv);
        nrmv = pk_fma(a4.hi, a4.hi, nrmv);
#pragma unroll
        for (int c = 0; c < KT; ++c) {
            v4f f4 = *(const v4f*)(tw + c * DD + kk4 * 4);   // uniform -> s_load
            dotv[c] = pk_fma_s(a4.lo, f4.lo, dotv[c]);
            dotv[c] = pk_fma_s(a4.hi, f4.hi, dotv[c]);
        }
    }
    float nrm_own = nrmv.x + nrmv.y;

    // ---- mini-pass: center row from GLOBAL + template norms (k-distributed)
    float dot0[KT], nft[KT], n0p;
    {
        const float* row0 = x + (size_t)nodeC * DD + 8 * l;
        v4f z0 = *(const v4f*)(row0);
        v4f z1 = *(const v4f*)(row0 + 4);
        v2f nn = pk_fma(z0.lo, z0.lo, (v2f){0.f, 0.f});
        nn = pk_fma(z0.hi, z0.hi, nn);
        nn = pk_fma(z1.lo, z1.lo, nn);
        nn = pk_fma(z1.hi, z1.hi, nn);
        n0p = nn.x + nn.y;
#pragma unroll
        for (int c = 0; c < KT; ++c) {
            const float* tr = tw + c * DD + 8 * l;
            v4f t0_ = *(const v4f*)(tr);
            v4f t1_ = *(const v4f*)(tr + 4);
            v2f d = pk_fma(z0.lo, t0_.lo, (v2f){0.f, 0.f});
            d = pk_fma(z0.hi, t0_.hi, d);
            d = pk_fma(z1.lo, t1_.lo, d);
            d = pk_fma(z1.hi, t1_.hi, d);
            dot0[c] = d.x + d.y;
            v2f nf = pk_fma(t0_.lo, t0_.lo, (v2f){0.f, 0.f});
            nf = pk_fma(t0_.hi, t0_.hi, nf);
            nf = pk_fma(t1_.lo, t1_.lo, nf);
            nf = pk_fma(t1_.hi, t1_.hi, nf);
            nft[c] = nf.x + nf.y;
        }
        sum16x6(dot0[0], dot0[1], dot0[2], dot0[3], dot0[4], dot0[5]);
        sum16x5(dot0[6], dot0[7], dot0[8], dot0[9], n0p);
        sum16x5(nft[0], nft[1], nft[2], nft[3], nft[4]);
        sum16x5(nft[5], nft[6], nft[7], nft[8], nft[9]);
    }

    // ---- eM factors (1D registers)
    float eM_own[KT], eM0[KT];
#pragma unroll
    for (int c = 0; c < KT; ++c) {
        float mc0 = (n0p + nft[c] - 2.f * dot0[c]) * (1.f / DD);
        eM0[c] = FEXP2(-NLOG2E * mc0);
        float mcw = (nrm_own + nft[c] - 2.f * (dotv[c].x + dotv[c].y)) * (1.f / DD);
        eM_own[c] = FEXP2(-NLOG2E * mcw);
    }

    // ---- sFi now dead for ALL waves; overlay eM[w][p][j][c]
    __syncthreads();
    const int obase = (w * NPB + p) * (MM * KT);
    {
        const int rb = obase + (l + 1) * KT;
#pragma unroll
        for (int c = 0; c < KT; c += 2)
            *(v2f*)(&sFi[rb + c]) = (v2f){eM_own[c], eM_own[c + 1]};
        if (l == 0) {
#pragma unroll
            for (int c = 0; c < KT; c += 2)
                *(v2f*)(&sFi[obase + c]) = (v2f){eM0[c], eM0[c + 1]};
        }
    }
    // same-wave write->read: compiler-inserted lgkmcnt ordering suffices
    // (each wave reads only the [w][p] region its own lanes wrote).

    // ---- 2D roles
    const int rg = l & 3, cg = l >> 2;
    const int cbase = 2 * cg + (cg < 2 ? cg : 2);   // 0,3,6,8
    const bool isd = (cg >= 2);                     // slot 2 is a dummy col
    const int c2o = isd ? 0 : 2;                    // clamped slot-2 LDS offset

    // ---- Sinkhorn state (2D). Tp2 doubles as eK inside the outer iteration.
    float Tp2[4][3], TK0l[3], vv[3];
#pragma unroll
    for (int i2 = 0; i2 < 4; ++i2) {
        Tp2[i2][0] = 1.f / (MM * KT);
        Tp2[i2][1] = 1.f / (MM * KT);
        Tp2[i2][2] = isd ? 0.f : (1.f / (MM * KT));
    }
    TK0l[0] = 1.f / (MM * KT);
    TK0l[1] = 1.f / (MM * KT);
    TK0l[2] = isd ? 0.f : (1.f / (MM * KT));
    float u2[4] = {0.f, 0.f, 0.f, 0.f}, u0_ = 0.f;
    float eK0u[3] = {0.f, 0.f, 0.f};

#pragma unroll 1
    for (int outer = 0; outer < 5; ++outer) {
        // s[c] = col-sums of Tp (quad butterfly over rg) + row0 term
        float s0 = ((Tp2[0][0] + Tp2[1][0]) + (Tp2[2][0] + Tp2[3][0]));
        float s1 = ((Tp2[0][1] + Tp2[1][1]) + (Tp2[2][1] + Tp2[3][1]));
        float s2 = ((Tp2[0][2] + Tp2[1][2]) + (Tp2[2][2] + Tp2[3][2]));
        sumq3(s0, s1, s2);
        s0 += TK0l[0]; s1 += TK0l[1]; s2 += TK0l[2];

        // broadcast s and Tp0 (all 10 cols) to every lane
        float sa0 = __shfl(s0, gbase + 0, 64),  ta0 = __shfl(TK0l[0], gbase + 0, 64);
        float sa1 = __shfl(s1, gbase + 0, 64),  ta1 = __shfl(TK0l[1], gbase + 0, 64);
        float sa2 = __shfl(s2, gbase + 0, 64),  ta2 = __shfl(TK0l[2], gbase + 0, 64);
        float sa3 = __shfl(s0, gbase + 4, 64),  ta3 = __shfl(TK0l[0], gbase + 4, 64);
        float sa4 = __shfl(s1, gbase + 4, 64),  ta4 = __shfl(TK0l[1], gbase + 4, 64);
        float sa5 = __shfl(s2, gbase + 4, 64),  ta5 = __shfl(TK0l[2], gbase + 4, 64);
        float sa6 = __shfl(s0, gbase + 8, 64),  ta6 = __shfl(TK0l[0], gbase + 8, 64);
        float sa7 = __shfl(s1, gbase + 8, 64),  ta7 = __shfl(TK0l[1], gbase + 8, 64);
        float sa8 = __shfl(s0, gbase + 12, 64), ta8 = __shfl(TK0l[0], gbase + 12, 64);
        float sa9 = __shfl(s1, gbase + 12, 64), ta9 = __shfl(TK0l[1], gbase + 12, 64);

        // Cs/C0 on lane cl (Ct row reloaded from L1)
        v2f r0 = *(const v2f*)(ctp);
        v2f r1 = *(const v2f*)(ctp + 2);
        v2f r2 = *(const v2f*)(ctp + 4);
        v2f r3 = *(const v2f*)(ctp + 6);
        v2f r4 = *(const v2f*)(ctp + 8);
        float Cs, C0;
        {
            float a = r0.x * sa0,   b = r0.y * sa1;
            a = fmaf(r1.x, sa2, a); b = fmaf(r1.y, sa3, b);
            a = fmaf(r2.x, sa4, a); b = fmaf(r2.y, sa5, b);
            a = fmaf(r3.x, sa6, a); b = fmaf(r3.y, sa7, b);
            a = fmaf(r4.x, sa8, a); b = fmaf(r4.y, sa9, b);
            Cs = a + b;
            float q = r0.x * ta0,   d = r0.y * ta1;
            q = fmaf(r1.x, ta2, q); d = fmaf(r1.y, ta3, d);
            q = fmaf(r2.x, ta4, q); d = fmaf(r2.y, ta5, d);
            q = fmaf(r3.x, ta6, q); d = fmaf(r3.y, ta7, d);
            q = fmaf(r4.x, ta8, q); d = fmaf(r4.y, ta9, d);
            C0 = q + d;
        }
        float e0 = FEXP2(-TWO_LOG2E * ((16.f / 17.f) + ct2q - 2.f * Cs));
        float e1 = FEXP2(-TWO_LOG2E * ((1.f  / 17.f) + ct2q - 2.f * C0));

        // distribute E to the column owners
        float E1_0 = __shfl(e1, gbase + cbase + 0, 64);
        float E1_1 = __shfl(e1, gbase + cbase + 1, 64);
        float E1_2 = __shfl(e1, gbase + cbase + 2, 64);   // dummy: lane 10, x0 later
        float E0_0 = __shfl(e0, gbase + cbase + 0, 64);
        float E0_1 = __shfl(e0, gbase + cbase + 1, 64);
        float E0_2 = __shfl(e0, gbase + cbase + 2, 64);

        // mirror: Tp -> eK in place (eM streamed from the LDS overlay)
#pragma unroll
        for (int i2 = 0; i2 < 4; ++i2) {
            const int jb = obase + (1 + rg + 4 * i2) * KT + cbase;
            Tp2[i2][0] *= sFi[jb]       * E1_0;
            Tp2[i2][1] *= sFi[jb + 1]   * E1_1;
            Tp2[i2][2] *= sFi[jb + c2o] * E1_2;   // dummy lane: 0 * finite = 0
        }
        eK0u[0] = TK0l[0] * (sFi[obase + cbase]       * E0_0);
        eK0u[1] = TK0l[1] * (sFi[obase + cbase + 1]   * E0_1);
        eK0u[2] = TK0l[2] * (sFi[obase + cbase + c2o] * E0_2);
        float eK0cc2 = isd ? 1.f : eK0u[2];   // keeps dummy colacc > 0
        vv[0] = VV0; vv[1] = VV0; vv[2] = VV0;

        // inner 10 iterations
#pragma unroll 1
        for (int it = 0; it < 10; ++it) {
            // u-update: row partials over my 3 cols, butterfly over cg
            float p0 = Tp2[0][0] * vv[0];
            p0 = fmaf(Tp2[0][1], vv[1], p0); p0 = fmaf(Tp2[0][2], vv[2], p0);
            float p1 = Tp2[1][0] * vv[0];
            p1 = fmaf(Tp2[1][1], vv[1], p1); p1 = fmaf(Tp2[1][2], vv[2], p1);
            float p2 = Tp2[2][0] * vv[0];
            p2 = fmaf(Tp2[2][1], vv[1], p2); p2 = fmaf(Tp2[2][2], vv[2], p2);
            float p3 = Tp2[3][0] * vv[0];
            p3 = fmaf(Tp2[3][1], vv[1], p3); p3 = fmaf(Tp2[3][2], vv[2], p3);
            float p4 = eK0u[0] * vv[0];
            p4 = fmaf(eK0u[1], vv[1], p4); p4 = fmaf(eK0u[2], vv[2], p4);
            sums5(p0, p1, p2, p3, p4);
            u2[0] = RQP * FRCP(p0);
            u2[1] = RQP * FRCP(p1);
            u2[2] = RQP * FRCP(p2);
            u2[3] = RQP * FRCP(p3);
            u0_   = RQP * FRCP(p4);
            // v-update: col partials over my 4 rows, butterfly over rg
            float q0 = Tp2[0][0] * u2[0];
            q0 = fmaf(Tp2[1][0], u2[1], q0);
            q0 = fmaf(Tp2[2][0], u2[2], q0);
            q0 = fmaf(Tp2[3][0], u2[3], q0);
            float q1 = Tp2[0][1] * u2[0];
            q1 = fmaf(Tp2[1][1], u2[1], q1);
            q1 = fmaf(Tp2[2][1], u2[2], q1);
            q1 = fmaf(Tp2[3][1], u2[3], q1);
            float q2 = Tp2[0][2] * u2[0];
            q2 = fmaf(Tp2[1][2], u2[1], q2);
            q2 = fmaf(Tp2[2][2], u2[2], q2);
            q2 = fmaf(Tp2[3][2], u2[3], q2);
            sumq3(q0, q1, q2);
            vv[0] = FRCP(fmaf(eK0u[0], u0_, q0));
            vv[1] = FRCP(fmaf(eK0u[1], u0_, q1));
            vv[2] = FRCP(fmaf(eK0cc2, u0_, q2));
        }

        // eK -> Tp in place
        float puA = PWQP * u2[0], puB = PWQP * u2[1];
        float puC = PWQP * u2[2], puD = PWQP * u2[3];
        float pu0 = PWQP * u0_;
#pragma unroll
        for (int i = 0; i < 3; ++i) {
            Tp2[0][i] = (Tp2[0][i] * vv[i]) * puA;
            Tp2[1][i] = (Tp2[1][i] * vv[i]) * puB;
            Tp2[2][i] = (Tp2[2][i] * vv[i]) * puC;
            Tp2[3][i] = (Tp2[3][i] * vv[i]) * puD;
            TK0l[i]   = (eK0u[i]  * vv[i]) * pu0;
        }
    }

    // ---- final objective
    {
        float s0 = ((Tp2[0][0] + Tp2[1][0]) + (Tp2[2][0] + Tp2[3][0]));
        float s1 = ((Tp2[0][1] + Tp2[1][1]) + (Tp2[2][1] + Tp2[3][1]));
        float s2 = ((Tp2[0][2] + Tp2[1][2]) + (Tp2[2][2] + Tp2[3][2]));
        sumq3(s0, s1, s2);
        s0 += TK0l[0]; s1 += TK0l[1]; s2 += TK0l[2];
        float sa0 = __shfl(s0, gbase + 0, 64),  ta0 = __shfl(TK0l[0], gbase + 0, 64);
        float sa1 = __shfl(s1, gbase + 0, 64),  ta1 = __shfl(TK0l[1], gbase + 0, 64);
        float sa2 = __shfl(s2, gbase + 0, 64),  ta2 = __shfl(TK0l[2], gbase + 0, 64);
        float sa3 = __shfl(s0, gbase + 4, 64),  ta3 = __shfl(TK0l[0], gbase + 4, 64);
        float sa4 = __shfl(s1, gbase + 4, 64),  ta4 = __shfl(TK0l[1], gbase + 4, 64);
        float sa5 = __shfl(s2, gbase + 4, 64),  ta5 = __shfl(TK0l[2], gbase + 4, 64);
        float sa6 = __shfl(s0, gbase + 8, 64),  ta6 = __shfl(TK0l[0], gbase + 8, 64);
        float sa7 = __shfl(s1, gbase + 8, 64),  ta7 = __shfl(TK0l[1], gbase + 8, 64);
        float sa8 = __shfl(s0, gbase + 12, 64), ta8 = __shfl(TK0l[0], gbase + 12, 64);
        float sa9 = __shfl(s1, gbase + 12, 64), ta9 = __shfl(TK0l[1], gbase + 12, 64);
        v2f r0 = *(const v2f*)(ctp);
        v2f r1 = *(const v2f*)(ctp + 2);
        v2f r2 = *(const v2f*)(ctp + 4);
        v2f r3 = *(const v2f*)(ctp + 6);
        v2f r4 = *(const v2f*)(ctp + 8);
        float Cs, C0;
        {
            float a = r0.x * sa0,   b = r0.y * sa1;
            a = fmaf(r1.x, sa2, a); b = fmaf(r1.y, sa3, b);
            a = fmaf(r2.x, sa4, a); b = fmaf(r2.y, sa5, b);
            a = fmaf(r3.x, sa6, a); b = fmaf(r3.y, sa7, b);
            a = fmaf(r4.x, sa8, a); b = fmaf(r4.y, sa9, b);
            Cs = a + b;
            float q = r0.x * ta0,   d = r0.y * ta1;
            q = fmaf(r1.x, ta2, q); d = fmaf(r1.y, ta3, d);
            q = fmaf(r2.x, ta4, q); d = fmaf(r2.y, ta5, d);
            q = fmaf(r3.x, ta6, q); d = fmaf(r3.y, ta7, d);
            q = fmaf(r4.x, ta8, q); d = fmaf(r4.y, ta9, d);
            C0 = q + d;
        }
        float g0l = (16.f / 17.f) + ct2q - 2.f * Cs;
        float g1l = (1.f  / 17.f) + ct2q - 2.f * C0;
        float G1_0 = __shfl(g1l, gbase + cbase + 0, 64);
        float G1_1 = __shfl(g1l, gbase + cbase + 1, 64);
        float G1_2 = __shfl(g1l, gbase + cbase + 2, 64);
        float G0_0 = __shfl(g0l, gbase + cbase + 0, 64);
        float G0_1 = __shfl(g0l, gbase + cbase + 1, 64);
        float G0_2 = __shfl(g0l, gbase + cbase + 2, 64);

        float objp = 0.f;
#pragma unroll
        for (int i2 = 0; i2 < 4; ++i2) {
            const int jb = obase + (1 + rg + 4 * i2) * KT + cbase;
            objp += Tp2[i2][0] * (-EPSLN2 * FLOG2(sFi[jb])       + 0.5f * G1_0);
            objp += Tp2[i2][1] * (-EPSLN2 * FLOG2(sFi[jb + 1])   + 0.5f * G1_1);
            objp += Tp2[i2][2] * (-EPSLN2 * FLOG2(sFi[jb + c2o]) + 0.5f * G1_2);
        }
        float obj0p = TK0l[0] * (-EPSLN2 * FLOG2(sFi[obase + cbase])       + 0.5f * G0_0);
        obj0p      += TK0l[1] * (-EPSLN2 * FLOG2(sFi[obase + cbase + 1])   + 0.5f * G0_1);
        obj0p      += TK0l[2] * (-EPSLN2 * FLOG2(sFi[obase + cbase + c2o]) + 0.5f * G0_2);
        float tot = objp + ((rg == 0) ? obj0p : 0.f);
        float obj = sum16(tot);
        if (l == 0 && node < N) out[node * TT + w] = obj;
    }
}

extern "C" void kernel_launch(void* const* d_in, const int* in_sizes, int n_in,
                              void* d_out, int out_size, void* d_ws, size_t ws_size,
                              hipStream_t stream) {
    const float* x    = (const float*)d_in[0];
    const int*   ei   = (const int*)d_in[1];
    const float* tmpl = (const float*)d_in[2];
    const float* tf   = (const float*)d_in[3];
    float* out = (float*)d_out;
    int N = in_sizes[0] / DD;
    int grid = (N + NPB - 1) / NPB;
    hipLaunchKernelGGL(ltfgw_kernel, dim3(grid), dim3(THREADS), 0, stream,
                       x, ei, tmpl, tf, out, N);
}

// Round 11
// 287.078 us; speedup vs baseline: 1.7414x; 1.2938x over previous
//
#include <hip/hip_runtime.h>

#define DEG 16
#define DD  128
#define KT  10      // template nodes (K)
#define TT  10      // templates
#define MM  17      // m = DEG+1
#define SLOTS 16    // node-slots per block (4 waves x 4 groups)
#define THREADS 256 // 4 independent waves; template = blockIdx.y
#define EMS 11      // eM overlay row stride (11*rg+cbase distinct mod 32)

#if __has_builtin(__builtin_amdgcn_exp2f)
#define FEXP2(x) __builtin_amdgcn_exp2f(x)
#else
#define FEXP2(x) exp2f(x)
#endif

#if __has_builtin(__builtin_amdgcn_rcpf)
#define FRCP(x) __builtin_amdgcn_rcpf(x)
#else
#define FRCP(x) (1.0f / (x))
#endif

#if __has_builtin(__builtin_amdgcn_logf)
#define FLOG2(x) __builtin_amdgcn_logf(x)
#else
#define FLOG2(x) __log2f(x)
#endif

// (1/EPS)*log2(e), EPS = 0.5
#define TWO_LOG2E 2.8853900817779268f
// log2(e): scale for the hoisted exp2 of 0.5*Mc
#define NLOG2E    1.4426950408889634f
// EPS*ln2 = 1/TWO_LOG2E: recovers 0.5*Mc from log2(eM)
#define EPSLN2    0.34657359027997264f
// QP = qw/pw = 17/10 folded into the u-update: RQP = 1/QP = 10/17
#define RQP       0.5882352941176471f
#define VV0       0.5882352941176471f
// pw*QP = 1/10 exactly
#define PWQP      0.1f

typedef float v2f __attribute__((ext_vector_type(2)));
typedef float v4f __attribute__((ext_vector_type(4)));

__device__ __forceinline__ v2f pk_fma(v2f a, v2f b, v2f c) {
    asm("v_pk_fma_f32 %0, %1, %2, %0" : "+v"(c) : "v"(a), "v"(b));
    return c;
}
__device__ __forceinline__ v2f pk_fma_s(v2f a, v2f bs, v2f c) {
    asm("v_pk_fma_f32 %0, %1, %2, %0" : "+v"(c) : "v"(a), "s"(bs));
    return c;
}

template <int CTRL>
__device__ __forceinline__ float dpp_add(float x) {
    union { float f; int i; } a, b;
    a.f = x;
    b.i = __builtin_amdgcn_update_dpp(0, a.i, CTRL, 0xF, 0xF, true);
    return x + b.f;
}
__device__ __forceinline__ float sum16(float t) {
    t = dpp_add<0xB1>(t);
    t = dpp_add<0x4E>(t);
    t = dpp_add<0x124>(t);
    t = dpp_add<0x128>(t);
    return t;
}

// hand-fused multi-value butterflies (v_add_f32_dpp); VALU->DPP hazard
// covered by entry s_nop 1 + interior spacing.
#define _D(i, CTRL) "v_add_f32_dpp %" #i ", %" #i ", %" #i " " CTRL \
                    " row_mask:0xf bank_mask:0xf bound_ctrl:0\n\t"
#define _C1 "quad_perm:[1,0,3,2]"
#define _C2 "quad_perm:[2,3,0,1]"
#define _C3 "row_ror:4"
#define _C4 "row_ror:8"

__device__ __forceinline__ void sum16x5(float& a0, float& a1, float& a2,
                                        float& a3, float& a4) {
    asm("s_nop 1\n\t"
        _D(0,_C1) _D(1,_C1) _D(2,_C1) _D(3,_C1) _D(4,_C1)
        _D(0,_C2) _D(1,_C2) _D(2,_C2) _D(3,_C2) _D(4,_C2)
        _D(0,_C3) _D(1,_C3) _D(2,_C3) _D(3,_C3) _D(4,_C3)
        _D(0,_C4) _D(1,_C4) _D(2,_C4) _D(3,_C4) _D(4,_C4)
        : "+v"(a0), "+v"(a1), "+v"(a2), "+v"(a3), "+v"(a4));
}
__device__ __forceinline__ void sum16x6(float& a0, float& a1, float& a2,
                                        float& a3, float& a4, float& a5) {
    asm("s_nop 1\n\t"
        _D(0,_C1) _D(1,_C1) _D(2,_C1) _D(3,_C1) _D(4,_C1) _D(5,_C1)
        _D(0,_C2) _D(1,_C2) _D(2,_C2) _D(3,_C2) _D(4,_C2) _D(5,_C2)
        _D(0,_C3) _D(1,_C3) _D(2,_C3) _D(3,_C3) _D(4,_C3) _D(5,_C3)
        _D(0,_C4) _D(1,_C4) _D(2,_C4) _D(3,_C4) _D(4,_C4) _D(5,_C4)
        : "+v"(a0), "+v"(a1), "+v"(a2), "+v"(a3), "+v"(a4), "+v"(a5));
}
// quad (over rg) butterfly, broadcast within each 4-lane quad
__device__ __forceinline__ void sumq3(float& a0, float& a1, float& a2) {
    asm("s_nop 1\n\t"
        _D(0,_C1) _D(1,_C1) _D(2,_C1)
        "s_nop 0\n\t"
        _D(0,_C2) _D(1,_C2) _D(2,_C2)
        : "+v"(a0), "+v"(a1), "+v"(a2));
}
// stride-4 (over cg) butterfly, broadcast
__device__ __forceinline__ void sums5(float& a0, float& a1, float& a2,
                                      float& a3, float& a4) {
    asm("s_nop 1\n\t"
        _D(0,_C3) _D(1,_C3) _D(2,_C3) _D(3,_C3) _D(4,_C3)
        _D(0,_C4) _D(1,_C4) _D(2,_C4) _D(3,_C4) _D(4,_C4)
        : "+v"(a0), "+v"(a1), "+v"(a2), "+v"(a3), "+v"(a4));
}

// R11 RESTRUCTURE: break the 10-wave block quantum. grid = (N/16, TT);
// 256-thread blocks of 4 INDEPENDENT waves (no __syncthreads anywhere).
// Each 16-lane group owns one node; template = blockIdx.y. x is 5MB and
// fully L2-resident, so neighbor rows are read straight from global in the
// M-phase (same scattered-16B pattern the old staging loop performed).
// LDS = only the eM 1D->2D overlay: 16 slots x 17 rows x stride 11 = 11968B.
// Residency is now wave-granular instead of 640-thread-granular.
__global__ __launch_bounds__(THREADS) void ltfgw_kernel(
    const float* __restrict__ x,      // [N,128]
    const int*   __restrict__ ei,     // edge_index[0], [N*DEG]
    const float* __restrict__ tmpl,   // [T,K,K]
    const float* __restrict__ tf,     // [T,K,128]
    float* __restrict__ out,          // [N,T]
    int N)
{
    __shared__ float sEM[SLOTS * MM * EMS];   // 11968 B

    const int tid  = threadIdx.x;
    const int t    = blockIdx.y;              // template (SGPR-uniform)
    const int slot = tid >> 4;                // node slot 0..15
    const int lane = tid & 63;
    const int l    = lane & 15;
    const int gbase = lane & ~15;
    const int node  = blockIdx.x * SLOTS + slot;
    const int nodeC = (node < N) ? node : (N - 1);

    const int cl = (l < KT) ? l : 0;
    const float* ctp = tmpl + ((size_t)t * KT + cl) * KT;
    const float* tw  = tf + (size_t)t * KT * DD;    // uniform -> s_load path

    // ---- ct2q = (Ct^2 @ q)[cl]
    float ct2q;
    {
        v2f r0 = *(const v2f*)(ctp);
        v2f r1 = *(const v2f*)(ctp + 2);
        v2f r2 = *(const v2f*)(ctp + 4);
        v2f r3 = *(const v2f*)(ctp + 6);
        v2f r4 = *(const v2f*)(ctp + 8);
        v2f acc = pk_fma(r0, r0, (v2f){0.f, 0.f});
        acc = pk_fma(r1, r1, acc);
        acc = pk_fma(r2, r2, acc);
        acc = pk_fma(r3, r3, acc);
        acc = pk_fma(r4, r4, acc);
        ct2q = (acc.x + acc.y) * (1.f / KT);
    }

    // ---- M main pass: own neighbor row from GLOBAL (L2-resident) vs
    // 10 template rows (wave-uniform -> SGPR operands)
    const int   srcl  = ei[nodeC * DEG + l];
    const float* myrow = x + (size_t)srcl * DD;
    v2f dotv[KT];
#pragma unroll
    for (int c = 0; c < KT; ++c) dotv[c] = (v2f){0.f, 0.f};
    v2f nrmv = (v2f){0.f, 0.f};
#pragma unroll 4
    for (int kk4 = 0; kk4 < 32; ++kk4) {
        v4f a4 = *(const v4f*)(myrow + kk4 * 4);
        nrmv = pk_fma(a4.lo, a4.lo, nrmv);
        nrmv = pk_fma(a4.hi, a4.hi, nrmv);
#pragma unroll
        for (int c = 0; c < KT; ++c) {
            v4f f4 = *(const v4f*)(tw + c * DD + kk4 * 4);   // s_load
            dotv[c] = pk_fma_s(a4.lo, f4.lo, dotv[c]);
            dotv[c] = pk_fma_s(a4.hi, f4.hi, dotv[c]);
        }
    }
    float nrm_own = nrmv.x + nrmv.y;

    // ---- mini-pass: center row (global, coalesced) + template norms
    float dot0[KT], nft[KT], n0p;
    {
        const float* row0 = x + (size_t)nodeC * DD + 8 * l;
        v4f z0 = *(const v4f*)(row0);
        v4f z1 = *(const v4f*)(row0 + 4);
        v2f nn = pk_fma(z0.lo, z0.lo, (v2f){0.f, 0.f});
        nn = pk_fma(z0.hi, z0.hi, nn);
        nn = pk_fma(z1.lo, z1.lo, nn);
        nn = pk_fma(z1.hi, z1.hi, nn);
        n0p = nn.x + nn.y;
#pragma unroll
        for (int c = 0; c < KT; ++c) {
            const float* tr = tw + c * DD + 8 * l;
            v4f t0_ = *(const v4f*)(tr);
            v4f t1_ = *(const v4f*)(tr + 4);
            v2f d = pk_fma(z0.lo, t0_.lo, (v2f){0.f, 0.f});
            d = pk_fma(z0.hi, t0_.hi, d);
            d = pk_fma(z1.lo, t1_.lo, d);
            d = pk_fma(z1.hi, t1_.hi, d);
            dot0[c] = d.x + d.y;
            v2f nf = pk_fma(t0_.lo, t0_.lo, (v2f){0.f, 0.f});
            nf = pk_fma(t0_.hi, t0_.hi, nf);
            nf = pk_fma(t1_.lo, t1_.lo, nf);
            nf = pk_fma(t1_.hi, t1_.hi, nf);
            nft[c] = nf.x + nf.y;
        }
        sum16x6(dot0[0], dot0[1], dot0[2], dot0[3], dot0[4], dot0[5]);
        sum16x5(dot0[6], dot0[7], dot0[8], dot0[9], n0p);
        sum16x5(nft[0], nft[1], nft[2], nft[3], nft[4]);
        sum16x5(nft[5], nft[6], nft[7], nft[8], nft[9]);
    }

    // ---- eM factors (1D), written to the LDS overlay for the 2D phase.
    // All traffic is within one wave: ds ordering (lgkmcnt) suffices,
    // no barrier needed.
    const int obase = slot * (MM * EMS);
    {
        const int rb = obase + (l + 1) * EMS;
#pragma unroll
        for (int c = 0; c < KT; c += 2) {
            float eA = FEXP2(-NLOG2E * ((nrm_own + nft[c] - 2.f * (dotv[c].x + dotv[c].y)) * (1.f / DD)));
            float eB = FEXP2(-NLOG2E * ((nrm_own + nft[c + 1] - 2.f * (dotv[c + 1].x + dotv[c + 1].y)) * (1.f / DD)));
            *(v2f*)(&sEM[rb + c]) = (v2f){eA, eB};
        }
        if (l == 0) {
#pragma unroll
            for (int c = 0; c < KT; c += 2) {
                float eA = FEXP2(-NLOG2E * ((n0p + nft[c] - 2.f * dot0[c]) * (1.f / DD)));
                float eB = FEXP2(-NLOG2E * ((n0p + nft[c + 1] - 2.f * dot0[c + 1]) * (1.f / DD)));
                *(v2f*)(&sEM[obase + c]) = (v2f){eA, eB};
            }
        }
    }

    // ---- 2D roles: lane = (rg, cg); rows {rg,rg+4,rg+8,rg+12}+1, cols
    // cbase..cbase+2 (10 cols split 3/3/2/2 + inert dummy for cg>=2)
    const int rg = l & 3, cg = l >> 2;
    const int cbase = 2 * cg + (cg < 2 ? cg : 2);   // 0,3,6,8
    const bool isd = (cg >= 2);
    const int c2o = isd ? 0 : 2;

    float Tp2[4][3], TK0l[3], vv[3];
#pragma unroll
    for (int i2 = 0; i2 < 4; ++i2) {
        Tp2[i2][0] = 1.f / (MM * KT);
        Tp2[i2][1] = 1.f / (MM * KT);
        Tp2[i2][2] = isd ? 0.f : (1.f / (MM * KT));
    }
    TK0l[0] = 1.f / (MM * KT);
    TK0l[1] = 1.f / (MM * KT);
    TK0l[2] = isd ? 0.f : (1.f / (MM * KT));
    float u2[4] = {0.f, 0.f, 0.f, 0.f}, u0_ = 0.f;
    float eK0u[3] = {0.f, 0.f, 0.f};

#pragma unroll 1
    for (int outer = 0; outer < 5; ++outer) {
        // col-sums of Tp (quad butterfly over rg) + row0 term
        float s0 = ((Tp2[0][0] + Tp2[1][0]) + (Tp2[2][0] + Tp2[3][0]));
        float s1 = ((Tp2[0][1] + Tp2[1][1]) + (Tp2[2][1] + Tp2[3][1]));
        float s2 = ((Tp2[0][2] + Tp2[1][2]) + (Tp2[2][2] + Tp2[3][2]));
        sumq3(s0, s1, s2);
        s0 += TK0l[0]; s1 += TK0l[1]; s2 += TK0l[2];

        float sa0 = __shfl(s0, gbase + 0, 64),  ta0 = __shfl(TK0l[0], gbase + 0, 64);
        float sa1 = __shfl(s1, gbase + 0, 64),  ta1 = __shfl(TK0l[1], gbase + 0, 64);
        float sa2 = __shfl(s2, gbase + 0, 64),  ta2 = __shfl(TK0l[2], gbase + 0, 64);
        float sa3 = __shfl(s0, gbase + 4, 64),  ta3 = __shfl(TK0l[0], gbase + 4, 64);
        float sa4 = __shfl(s1, gbase + 4, 64),  ta4 = __shfl(TK0l[1], gbase + 4, 64);
        float sa5 = __shfl(s2, gbase + 4, 64),  ta5 = __shfl(TK0l[2], gbase + 4, 64);
        float sa6 = __shfl(s0, gbase + 8, 64),  ta6 = __shfl(TK0l[0], gbase + 8, 64);
        float sa7 = __shfl(s1, gbase + 8, 64),  ta7 = __shfl(TK0l[1], gbase + 8, 64);
        float sa8 = __shfl(s0, gbase + 12, 64), ta8 = __shfl(TK0l[0], gbase + 12, 64);
        float sa9 = __shfl(s1, gbase + 12, 64), ta9 = __shfl(TK0l[1], gbase + 12, 64);

        v2f r0 = *(const v2f*)(ctp);
        v2f r1 = *(const v2f*)(ctp + 2);
        v2f r2 = *(const v2f*)(ctp + 4);
        v2f r3 = *(const v2f*)(ctp + 6);
        v2f r4 = *(const v2f*)(ctp + 8);
        float Cs, C0;
        {
            float a = r0.x * sa0,   b = r0.y * sa1;
            a = fmaf(r1.x, sa2, a); b = fmaf(r1.y, sa3, b);
            a = fmaf(r2.x, sa4, a); b = fmaf(r2.y, sa5, b);
            a = fmaf(r3.x, sa6, a); b = fmaf(r3.y, sa7, b);
            a = fmaf(r4.x, sa8, a); b = fmaf(r4.y, sa9, b);
            Cs = a + b;
            float q = r0.x * ta0,   d = r0.y * ta1;
            q = fmaf(r1.x, ta2, q); d = fmaf(r1.y, ta3, d);
            q = fmaf(r2.x, ta4, q); d = fmaf(r2.y, ta5, d);
            q = fmaf(r3.x, ta6, q); d = fmaf(r3.y, ta7, d);
            q = fmaf(r4.x, ta8, q); d = fmaf(r4.y, ta9, d);
            C0 = q + d;
        }
        float e0 = FEXP2(-TWO_LOG2E * ((16.f / 17.f) + ct2q - 2.f * Cs));
        float e1 = FEXP2(-TWO_LOG2E * ((1.f  / 17.f) + ct2q - 2.f * C0));

        float E1_0 = __shfl(e1, gbase + cbase + 0, 64);
        float E1_1 = __shfl(e1, gbase + cbase + 1, 64);
        float E1_2 = __shfl(e1, gbase + cbase + 2, 64);
        float E0_0 = __shfl(e0, gbase + cbase + 0, 64);
        float E0_1 = __shfl(e0, gbase + cbase + 1, 64);
        float E0_2 = __shfl(e0, gbase + cbase + 2, 64);

        // mirror: Tp -> eK in place (eM streamed from the LDS overlay)
#pragma unroll
        for (int i2 = 0; i2 < 4; ++i2) {
            const int jb = obase + (1 + rg + 4 * i2) * EMS + cbase;
            Tp2[i2][0] *= sEM[jb]       * E1_0;
            Tp2[i2][1] *= sEM[jb + 1]   * E1_1;
            Tp2[i2][2] *= sEM[jb + c2o] * E1_2;   // dummy: 0 * finite = 0
        }
        eK0u[0] = TK0l[0] * (sEM[obase + cbase]       * E0_0);
        eK0u[1] = TK0l[1] * (sEM[obase + cbase + 1]   * E0_1);
        eK0u[2] = TK0l[2] * (sEM[obase + cbase + c2o] * E0_2);
        float eK0cc2 = isd ? 1.f : eK0u[2];   // keeps dummy colacc > 0
        vv[0] = VV0; vv[1] = VV0; vv[2] = VV0;

#pragma unroll 1
        for (int it = 0; it < 10; ++it) {
            float p0 = Tp2[0][0] * vv[0];
            p0 = fmaf(Tp2[0][1], vv[1], p0); p0 = fmaf(Tp2[0][2], vv[2], p0);
            float p1 = Tp2[1][0] * vv[0];
            p1 = fmaf(Tp2[1][1], vv[1], p1); p1 = fmaf(Tp2[1][2], vv[2], p1);
            float p2 = Tp2[2][0] * vv[0];
            p2 = fmaf(Tp2[2][1], vv[1], p2); p2 = fmaf(Tp2[2][2], vv[2], p2);
            float p3 = Tp2[3][0] * vv[0];
            p3 = fmaf(Tp2[3][1], vv[1], p3); p3 = fmaf(Tp2[3][2], vv[2], p3);
            float p4 = eK0u[0] * vv[0];
            p4 = fmaf(eK0u[1], vv[1], p4); p4 = fmaf(eK0u[2], vv[2], p4);
            sums5(p0, p1, p2, p3, p4);
            u2[0] = RQP * FRCP(p0);
            u2[1] = RQP * FRCP(p1);
            u2[2] = RQP * FRCP(p2);
            u2[3] = RQP * FRCP(p3);
            u0_   = RQP * FRCP(p4);
            float q0 = Tp2[0][0] * u2[0];
            q0 = fmaf(Tp2[1][0], u2[1], q0);
            q0 = fmaf(Tp2[2][0], u2[2], q0);
            q0 = fmaf(Tp2[3][0], u2[3], q0);
            float q1 = Tp2[0][1] * u2[0];
            q1 = fmaf(Tp2[1][1], u2[1], q1);
            q1 = fmaf(Tp2[2][1], u2[2], q1);
            q1 = fmaf(Tp2[3][1], u2[3], q1);
            float q2 = Tp2[0][2] * u2[0];
            q2 = fmaf(Tp2[1][2], u2[1], q2);
            q2 = fmaf(Tp2[2][2], u2[2], q2);
            q2 = fmaf(Tp2[3][2], u2[3], q2);
            sumq3(q0, q1, q2);
            vv[0] = FRCP(fmaf(eK0u[0], u0_, q0));
            vv[1] = FRCP(fmaf(eK0u[1], u0_, q1));
            vv[2] = FRCP(fmaf(eK0cc2, u0_, q2));
        }

        float puA = PWQP * u2[0], puB = PWQP * u2[1];
        float puC = PWQP * u2[2], puD = PWQP * u2[3];
        float pu0 = PWQP * u0_;
#pragma unroll
        for (int i = 0; i < 3; ++i) {
            Tp2[0][i] = (Tp2[0][i] * vv[i]) * puA;
            Tp2[1][i] = (Tp2[1][i] * vv[i]) * puB;
            Tp2[2][i] = (Tp2[2][i] * vv[i]) * puC;
            Tp2[3][i] = (Tp2[3][i] * vv[i]) * puD;
            TK0l[i]   = (eK0u[i]  * vv[i]) * pu0;
        }
    }

    // ---- final objective
    {
        float s0 = ((Tp2[0][0] + Tp2[1][0]) + (Tp2[2][0] + Tp2[3][0]));
        float s1 = ((Tp2[0][1] + Tp2[1][1]) + (Tp2[2][1] + Tp2[3][1]));
        float s2 = ((Tp2[0][2] + Tp2[1][2]) + (Tp2[2][2] + Tp2[3][2]));
        sumq3(s0, s1, s2);
        s0 += TK0l[0]; s1 += TK0l[1]; s2 += TK0l[2];
        float sa0 = __shfl(s0, gbase + 0, 64),  ta0 = __shfl(TK0l[0], gbase + 0, 64);
        float sa1 = __shfl(s1, gbase + 0, 64),  ta1 = __shfl(TK0l[1], gbase + 0, 64);
        float sa2 = __shfl(s2, gbase + 0, 64),  ta2 = __shfl(TK0l[2], gbase + 0, 64);
        float sa3 = __shfl(s0, gbase + 4, 64),  ta3 = __shfl(TK0l[0], gbase + 4, 64);
        float sa4 = __shfl(s1, gbase + 4, 64),  ta4 = __shfl(TK0l[1], gbase + 4, 64);
        float sa5 = __shfl(s2, gbase + 4, 64),  ta5 = __shfl(TK0l[2], gbase + 4, 64);
        float sa6 = __shfl(s0, gbase + 8, 64),  ta6 = __shfl(TK0l[0], gbase + 8, 64);
        float sa7 = __shfl(s1, gbase + 8, 64),  ta7 = __shfl(TK0l[1], gbase + 8, 64);
        float sa8 = __shfl(s0, gbase + 12, 64), ta8 = __shfl(TK0l[0], gbase + 12, 64);
        float sa9 = __shfl(s1, gbase + 12, 64), ta9 = __shfl(TK0l[1], gbase + 12, 64);
        v2f r0 = *(const v2f*)(ctp);
        v2f r1 = *(const v2f*)(ctp + 2);
        v2f r2 = *(const v2f*)(ctp + 4);
        v2f r3 = *(const v2f*)(ctp + 6);
        v2f r4 = *(const v2f*)(ctp + 8);
        float Cs, C0;
        {
            float a = r0.x * sa0,   b = r0.y * sa1;
            a = fmaf(r1.x, sa2, a); b = fmaf(r1.y, sa3, b);
            a = fmaf(r2.x, sa4, a); b = fmaf(r2.y, sa5, b);
            a = fmaf(r3.x, sa6, a); b = fmaf(r3.y, sa7, b);
            a = fmaf(r4.x, sa8, a); b = fmaf(r4.y, sa9, b);
            Cs = a + b;
            float q = r0.x * ta0,   d = r0.y * ta1;
            q = fmaf(r1.x, ta2, q); d = fmaf(r1.y, ta3, d);
            q = fmaf(r2.x, ta4, q); d = fmaf(r2.y, ta5, d);
            q = fmaf(r3.x, ta6, q); d = fmaf(r3.y, ta7, d);
            q = fmaf(r4.x, ta8, q); d = fmaf(r4.y, ta9, d);
            C0 = q + d;
        }
        float g0l = (16.f / 17.f) + ct2q - 2.f * Cs;
        float g1l = (1.f  / 17.f) + ct2q - 2.f * C0;
        float G1_0 = __shfl(g1l, gbase + cbase + 0, 64);
        float G1_1 = __shfl(g1l, gbase + cbase + 1, 64);
        float G1_2 = __shfl(g1l, gbase + cbase + 2, 64);
        float G0_0 = __shfl(g0l, gbase + cbase + 0, 64);
        float G0_1 = __shfl(g0l, gbase + cbase + 1, 64);
        float G0_2 = __shfl(g0l, gbase + cbase + 2, 64);

        float objp = 0.f;
#pragma unroll
        for (int i2 = 0; i2 < 4; ++i2) {
            const int jb = obase + (1 + rg + 4 * i2) * EMS + cbase;
            objp += Tp2[i2][0] * (-EPSLN2 * FLOG2(sEM[jb])       + 0.5f * G1_0);
            objp += Tp2[i2][1] * (-EPSLN2 * FLOG2(sEM[jb + 1])   + 0.5f * G1_1);
            objp += Tp2[i2][2] * (-EPSLN2 * FLOG2(sEM[jb + c2o]) + 0.5f * G1_2);
        }
        float obj0p = TK0l[0] * (-EPSLN2 * FLOG2(sEM[obase + cbase])       + 0.5f * G0_0);
        obj0p      += TK0l[1] * (-EPSLN2 * FLOG2(sEM[obase + cbase + 1])   + 0.5f * G0_1);
        obj0p      += TK0l[2] * (-EPSLN2 * FLOG2(sEM[obase + cbase + c2o]) + 0.5f * G0_2);
        float tot = objp + ((rg == 0) ? obj0p : 0.f);
        float obj = sum16(tot);
        if (l == 0 && node < N) out[node * TT + t] = obj;
    }
}

extern "C" void kernel_launch(void* const* d_in, const int* in_sizes, int n_in,
                              void* d_out, int out_size, void* d_ws, size_t ws_size,
                              hipStream_t stream) {
    const float* x    = (const float*)d_in[0];
    const int*   ei   = (const int*)d_in[1];
    const float* tmpl = (const float*)d_in[2];
    const float* tf   = (const float*)d_in[3];
    float* out = (float*)d_out;
    int N = in_sizes[0] / DD;
    int gx = (N + SLOTS - 1) / SLOTS;
    hipLaunchKernelGGL(ltfgw_kernel, dim3(gx, TT), dim3(THREADS), 0, stream,
                       x, ei, tmpl, tf, out, N);
}

// Round 13
// 279.863 us; speedup vs baseline: 1.7863x; 1.0258x over previous
//
#include <hip/hip_runtime.h>

#define DEG 16
#define DD  128
#define KT  10      // template nodes (K)
#define TT  10      // templates
#define MM  17      // m = DEG+1
#define SLOTS 16    // node-slots per block (4 waves x 4 groups)
#define THREADS 256 // 4 independent waves
#define EMS 11      // eM overlay row stride

#if __has_builtin(__builtin_amdgcn_exp2f)
#define FEXP2(x) __builtin_amdgcn_exp2f(x)
#else
#define FEXP2(x) exp2f(x)
#endif

#if __has_builtin(__builtin_amdgcn_rcpf)
#define FRCP(x) __builtin_amdgcn_rcpf(x)
#else
#define FRCP(x) (1.0f / (x))
#endif

#if __has_builtin(__builtin_amdgcn_logf)
#define FLOG2(x) __builtin_amdgcn_logf(x)
#else
#define FLOG2(x) __log2f(x)
#endif

// (1/EPS)*log2(e), EPS = 0.5
#define TWO_LOG2E 2.8853900817779268f
#define NLOG2E    1.4426950408889634f
#define EPSLN2    0.34657359027997264f
// pw*QP = 1/10 exactly. Scale-invariant inner loop: RQP removed -- the
// scale factor cancels exactly in the u*vv product that forms Tp.
#define PWQP      0.1f

typedef float v2f __attribute__((ext_vector_type(2)));
typedef float v4f __attribute__((ext_vector_type(4)));

// NOTE (R12 lesson): v_pk_*_f32 requires 64-bit register-PAIR operands in
// every source slot; op_sel_hi cannot widen a single VGPR scalar. Broadcast
// variants removed.
__device__ __forceinline__ v2f pk_fma(v2f a, v2f b, v2f c) {
    asm("v_pk_fma_f32 %0, %1, %2, %0" : "+v"(c) : "v"(a), "v"(b));
    return c;
}
__device__ __forceinline__ v2f pk_fma_s(v2f a, v2f bs, v2f c) {
    asm("v_pk_fma_f32 %0, %1, %2, %0" : "+v"(c) : "v"(a), "s"(bs));
    return c;
}

template <int CTRL>
__device__ __forceinline__ float dpp_add(float x) {
    union { float f; int i; } a, b;
    a.f = x;
    b.i = __builtin_amdgcn_update_dpp(0, a.i, CTRL, 0xF, 0xF, true);
    return x + b.f;
}
__device__ __forceinline__ float sum16(float t) {
    t = dpp_add<0xB1>(t);
    t = dpp_add<0x4E>(t);
    t = dpp_add<0x124>(t);
    t = dpp_add<0x128>(t);
    return t;
}

#define _D(i, CTRL) "v_add_f32_dpp %" #i ", %" #i ", %" #i " " CTRL \
                    " row_mask:0xf bank_mask:0xf bound_ctrl:0\n\t"
#define _C1 "quad_perm:[1,0,3,2]"
#define _C2 "quad_perm:[2,3,0,1]"
#define _C3 "row_ror:4"
#define _C4 "row_ror:8"

__device__ __forceinline__ void sum16x5(float& a0, float& a1, float& a2,
                                        float& a3, float& a4) {
    asm("s_nop 1\n\t"
        _D(0,_C1) _D(1,_C1) _D(2,_C1) _D(3,_C1) _D(4,_C1)
        _D(0,_C2) _D(1,_C2) _D(2,_C2) _D(3,_C2) _D(4,_C2)
        _D(0,_C3) _D(1,_C3) _D(2,_C3) _D(3,_C3) _D(4,_C3)
        _D(0,_C4) _D(1,_C4) _D(2,_C4) _D(3,_C4) _D(4,_C4)
        : "+v"(a0), "+v"(a1), "+v"(a2), "+v"(a3), "+v"(a4));
}
__device__ __forceinline__ void sum16x6(float& a0, float& a1, float& a2,
                                        float& a3, float& a4, float& a5) {
    asm("s_nop 1\n\t"
        _D(0,_C1) _D(1,_C1) _D(2,_C1) _D(3,_C1) _D(4,_C1) _D(5,_C1)
        _D(0,_C2) _D(1,_C2) _D(2,_C2) _D(3,_C2) _D(4,_C2) _D(5,_C2)
        _D(0,_C3) _D(1,_C3) _D(2,_C3) _D(3,_C3) _D(4,_C3) _D(5,_C3)
        _D(0,_C4) _D(1,_C4) _D(2,_C4) _D(3,_C4) _D(4,_C4) _D(5,_C4)
        : "+v"(a0), "+v"(a1), "+v"(a2), "+v"(a3), "+v"(a4), "+v"(a5));
}
__device__ __forceinline__ void sumq3(float& a0, float& a1, float& a2) {
    asm("s_nop 1\n\t"
        _D(0,_C1) _D(1,_C1) _D(2,_C1)
        "s_nop 0\n\t"
        _D(0,_C2) _D(1,_C2) _D(2,_C2)
        : "+v"(a0), "+v"(a1), "+v"(a2));
}
__device__ __forceinline__ void sums5(float& a0, float& a1, float& a2,
                                      float& a3, float& a4) {
    asm("s_nop 1\n\t"
        _D(0,_C3) _D(1,_C3) _D(2,_C3) _D(3,_C3) _D(4,_C3)
        _D(0,_C4) _D(1,_C4) _D(2,_C4) _D(3,_C4) _D(4,_C4)
        : "+v"(a0), "+v"(a1), "+v"(a2), "+v"(a3), "+v"(a4));
}

// R13 = R11 structure + (a) scale-invariant inner loop (no RQP muls) and
// (c) XCD-swizzled grid (10 template-blocks per node-range share an XCD's
// L2). The R12 packed-broadcast q-update is reverted (ISA constraint).
__global__ __launch_bounds__(THREADS) void ltfgw_kernel(
    const float* __restrict__ x,      // [N,128]
    const int*   __restrict__ ei,     // edge_index[0], [N*DEG]
    const float* __restrict__ tmpl,   // [T,K,K]
    const float* __restrict__ tf,     // [T,K,128]
    float* __restrict__ out,          // [N,T]
    int N)
{
    __shared__ float sEM[SLOTS * MM * EMS];   // 11968 B

    const int tid  = threadIdx.x;
    // XCD-swizzle decode: phys%8 = XCD (dispatch round-robin); on each XCD,
    // k=phys>>3 enumerates (template fastest, then node-range).
    const int phys = blockIdx.x;
    const int xcd  = phys & 7;
    const int k    = phys >> 3;
    const int t    = k % TT;
    const int bx   = xcd + 8 * (k / TT);

    const int slot = tid >> 4;
    const int lane = tid & 63;
    const int l    = lane & 15;
    const int gbase = lane & ~15;
    const int node  = bx * SLOTS + slot;
    const int nodeC = (node < N) ? node : (N - 1);

    const int cl = (l < KT) ? l : 0;
    const float* ctp = tmpl + ((size_t)t * KT + cl) * KT;
    const float* tw  = tf + (size_t)t * KT * DD;

    // ---- ct2q = (Ct^2 @ q)[cl]
    float ct2q;
    {
        v2f r0 = *(const v2f*)(ctp);
        v2f r1 = *(const v2f*)(ctp + 2);
        v2f r2 = *(const v2f*)(ctp + 4);
        v2f r3 = *(const v2f*)(ctp + 6);
        v2f r4 = *(const v2f*)(ctp + 8);
        v2f acc = pk_fma(r0, r0, (v2f){0.f, 0.f});
        acc = pk_fma(r1, r1, acc);
        acc = pk_fma(r2, r2, acc);
        acc = pk_fma(r3, r3, acc);
        acc = pk_fma(r4, r4, acc);
        ct2q = (acc.x + acc.y) * (1.f / KT);
    }

    // ---- M main pass: own neighbor row from GLOBAL (L2-resident) vs
    // 10 template rows (wave-uniform -> SGPR operands)
    const int   srcl  = ei[nodeC * DEG + l];
    const float* myrow = x + (size_t)srcl * DD;
    v2f dotv[KT];
#pragma unroll
    for (int c = 0; c < KT; ++c) dotv[c] = (v2f){0.f, 0.f};
    v2f nrmv = (v2f){0.f, 0.f};
#pragma unroll 4
    for (int kk4 = 0; kk4 < 32; ++kk4) {
        v4f a4 = *(const v4f*)(myrow + kk4 * 4);
        nrmv = pk_fma(a4.lo, a4.lo, nrmv);
        nrmv = pk_fma(a4.hi, a4.hi, nrmv);
#pragma unroll
        for (int c = 0; c < KT; ++c) {
            v4f f4 = *(const v4f*)(tw + c * DD + kk4 * 4);   // s_load
            dotv[c] = pk_fma_s(a4.lo, f4.lo, dotv[c]);
            dotv[c] = pk_fma_s(a4.hi, f4.hi, dotv[c]);
        }
    }
    float nrm_own = nrmv.x + nrmv.y;

    // ---- mini-pass: center row (global, coalesced) + template norms
    float dot0[KT], nft[KT], n0p;
    {
        const float* row0 = x + (size_t)nodeC * DD + 8 * l;
        v4f z0 = *(const v4f*)(row0);
        v4f z1 = *(const v4f*)(row0 + 4);
        v2f nn = pk_fma(z0.lo, z0.lo, (v2f){0.f, 0.f});
        nn = pk_fma(z0.hi, z0.hi, nn);
        nn = pk_fma(z1.lo, z1.lo, nn);
        nn = pk_fma(z1.hi, z1.hi, nn);
        n0p = nn.x + nn.y;
#pragma unroll
        for (int c = 0; c < KT; ++c) {
            const float* tr = tw + c * DD + 8 * l;
            v4f t0_ = *(const v4f*)(tr);
            v4f t1_ = *(const v4f*)(tr + 4);
            v2f d = pk_fma(z0.lo, t0_.lo, (v2f){0.f, 0.f});
            d = pk_fma(z0.hi, t0_.hi, d);
            d = pk_fma(z1.lo, t1_.lo, d);
            d = pk_fma(z1.hi, t1_.hi, d);
            dot0[c] = d.x + d.y;
            v2f nf = pk_fma(t0_.lo, t0_.lo, (v2f){0.f, 0.f});
            nf = pk_fma(t0_.hi, t0_.hi, nf);
            nf = pk_fma(t1_.lo, t1_.lo, nf);
            nf = pk_fma(t1_.hi, t1_.hi, nf);
            nft[c] = nf.x + nf.y;
        }
        sum16x6(dot0[0], dot0[1], dot0[2], dot0[3], dot0[4], dot0[5]);
        sum16x5(dot0[6], dot0[7], dot0[8], dot0[9], n0p);
        sum16x5(nft[0], nft[1], nft[2], nft[3], nft[4]);
        sum16x5(nft[5], nft[6], nft[7], nft[8], nft[9]);
    }

    // ---- eM factors -> LDS overlay (same-wave traffic, lgkm-ordered)
    const int obase = slot * (MM * EMS);
    {
        const int rb = obase + (l + 1) * EMS;
#pragma unroll
        for (int c = 0; c < KT; c += 2) {
            float eA = FEXP2(-NLOG2E * ((nrm_own + nft[c] - 2.f * (dotv[c].x + dotv[c].y)) * (1.f / DD)));
            float eB = FEXP2(-NLOG2E * ((nrm_own + nft[c + 1] - 2.f * (dotv[c + 1].x + dotv[c + 1].y)) * (1.f / DD)));
            *(v2f*)(&sEM[rb + c]) = (v2f){eA, eB};
        }
        if (l == 0) {
#pragma unroll
            for (int c = 0; c < KT; c += 2) {
                float eA = FEXP2(-NLOG2E * ((n0p + nft[c] - 2.f * dot0[c]) * (1.f / DD)));
                float eB = FEXP2(-NLOG2E * ((n0p + nft[c + 1] - 2.f * dot0[c + 1]) * (1.f / DD)));
                *(v2f*)(&sEM[obase + c]) = (v2f){eA, eB};
            }
        }
    }

    // ---- 2D roles
    const int rg = l & 3, cg = l >> 2;
    const int cbase = 2 * cg + (cg < 2 ? cg : 2);   // 0,3,6,8
    const bool isd = (cg >= 2);
    const int c2o = isd ? 0 : 2;

    float Tp2[4][3], TK0l[3];
    float vv0, vv1, vv2;
#pragma unroll
    for (int i2 = 0; i2 < 4; ++i2) {
        Tp2[i2][0] = 1.f / (MM * KT);
        Tp2[i2][1] = 1.f / (MM * KT);
        Tp2[i2][2] = isd ? 0.f : (1.f / (MM * KT));
    }
    TK0l[0] = 1.f / (MM * KT);
    TK0l[1] = 1.f / (MM * KT);
    TK0l[2] = isd ? 0.f : (1.f / (MM * KT));
    float u2[4] = {0.f, 0.f, 0.f, 0.f}, u0_ = 0.f;
    float eK0u[3] = {0.f, 0.f, 0.f};

#pragma unroll 1
    for (int outer = 0; outer < 5; ++outer) {
        // col-sums of Tp (quad butterfly over rg) + row0 term
        float s0 = ((Tp2[0][0] + Tp2[1][0]) + (Tp2[2][0] + Tp2[3][0]));
        float s1 = ((Tp2[0][1] + Tp2[1][1]) + (Tp2[2][1] + Tp2[3][1]));
        float s2 = ((Tp2[0][2] + Tp2[1][2]) + (Tp2[2][2] + Tp2[3][2]));
        sumq3(s0, s1, s2);
        s0 += TK0l[0]; s1 += TK0l[1]; s2 += TK0l[2];

        float sa0 = __shfl(s0, gbase + 0, 64),  ta0 = __shfl(TK0l[0], gbase + 0, 64);
        float sa1 = __shfl(s1, gbase + 0, 64),  ta1 = __shfl(TK0l[1], gbase + 0, 64);
        float sa2 = __shfl(s2, gbase + 0, 64),  ta2 = __shfl(TK0l[2], gbase + 0, 64);
        float sa3 = __shfl(s0, gbase + 4, 64),  ta3 = __shfl(TK0l[0], gbase + 4, 64);
        float sa4 = __shfl(s1, gbase + 4, 64),  ta4 = __shfl(TK0l[1], gbase + 4, 64);
        float sa5 = __shfl(s2, gbase + 4, 64),  ta5 = __shfl(TK0l[2], gbase + 4, 64);
        float sa6 = __shfl(s0, gbase + 8, 64),  ta6 = __shfl(TK0l[0], gbase + 8, 64);
        float sa7 = __shfl(s1, gbase + 8, 64),  ta7 = __shfl(TK0l[1], gbase + 8, 64);
        float sa8 = __shfl(s0, gbase + 12, 64), ta8 = __shfl(TK0l[0], gbase + 12, 64);
        float sa9 = __shfl(s1, gbase + 12, 64), ta9 = __shfl(TK0l[1], gbase + 12, 64);

        v2f r0 = *(const v2f*)(ctp);
        v2f r1 = *(const v2f*)(ctp + 2);
        v2f r2 = *(const v2f*)(ctp + 4);
        v2f r3 = *(const v2f*)(ctp + 6);
        v2f r4 = *(const v2f*)(ctp + 8);
        float Cs, C0;
        {
            float a = r0.x * sa0,   b = r0.y * sa1;
            a = fmaf(r1.x, sa2, a); b = fmaf(r1.y, sa3, b);
            a = fmaf(r2.x, sa4, a); b = fmaf(r2.y, sa5, b);
            a = fmaf(r3.x, sa6, a); b = fmaf(r3.y, sa7, b);
            a = fmaf(r4.x, sa8, a); b = fmaf(r4.y, sa9, b);
            Cs = a + b;
            float q = r0.x * ta0,   d = r0.y * ta1;
            q = fmaf(r1.x, ta2, q); d = fmaf(r1.y, ta3, d);
            q = fmaf(r2.x, ta4, q); d = fmaf(r2.y, ta5, d);
            q = fmaf(r3.x, ta6, q); d = fmaf(r3.y, ta7, d);
            q = fmaf(r4.x, ta8, q); d = fmaf(r4.y, ta9, d);
            C0 = q + d;
        }
        float e0 = FEXP2(-TWO_LOG2E * ((16.f / 17.f) + ct2q - 2.f * Cs));
        float e1 = FEXP2(-TWO_LOG2E * ((1.f  / 17.f) + ct2q - 2.f * C0));

        float E1_0 = __shfl(e1, gbase + cbase + 0, 64);
        float E1_1 = __shfl(e1, gbase + cbase + 1, 64);
        float E1_2 = __shfl(e1, gbase + cbase + 2, 64);
        float E0_0 = __shfl(e0, gbase + cbase + 0, 64);
        float E0_1 = __shfl(e0, gbase + cbase + 1, 64);
        float E0_2 = __shfl(e0, gbase + cbase + 2, 64);

        // mirror: Tp -> eK in place (eM streamed from LDS)
#pragma unroll
        for (int i2 = 0; i2 < 4; ++i2) {
            const int jb = obase + (1 + rg + 4 * i2) * EMS + cbase;
            Tp2[i2][0] *= sEM[jb]       * E1_0;
            Tp2[i2][1] *= sEM[jb + 1]   * E1_1;
            Tp2[i2][2] *= sEM[jb + c2o] * E1_2;   // dummy: 0 * finite = 0
        }
        eK0u[0] = TK0l[0] * (sEM[obase + cbase]       * E0_0);
        eK0u[1] = TK0l[1] * (sEM[obase + cbase + 1]   * E0_1);
        eK0u[2] = TK0l[2] * (sEM[obase + cbase + c2o] * E0_2);
        float eK0cc2 = isd ? 1.f : eK0u[2];   // keeps dummy colacc > 0
        // scale-invariant domain: vv starts at 1; no RQP anywhere inside.
        vv0 = 1.f; vv1 = 1.f; vv2 = 1.f;

#pragma unroll 1
        for (int it = 0; it < 10; ++it) {
            // u-update: row partials over my 3 cols, butterfly over cg
            float p0 = Tp2[0][0] * vv0;
            p0 = fmaf(Tp2[0][1], vv1, p0); p0 = fmaf(Tp2[0][2], vv2, p0);
            float p1 = Tp2[1][0] * vv0;
            p1 = fmaf(Tp2[1][1], vv1, p1); p1 = fmaf(Tp2[1][2], vv2, p1);
            float p2 = Tp2[2][0] * vv0;
            p2 = fmaf(Tp2[2][1], vv1, p2); p2 = fmaf(Tp2[2][2], vv2, p2);
            float p3 = Tp2[3][0] * vv0;
            p3 = fmaf(Tp2[3][1], vv1, p3); p3 = fmaf(Tp2[3][2], vv2, p3);
            float p4 = eK0u[0] * vv0;
            p4 = fmaf(eK0u[1], vv1, p4); p4 = fmaf(eK0u[2], vv2, p4);
            sums5(p0, p1, p2, p3, p4);
            u2[0] = FRCP(p0);
            u2[1] = FRCP(p1);
            u2[2] = FRCP(p2);
            u2[3] = FRCP(p3);
            u0_   = FRCP(p4);
            // v-update: col partials over my 4 rows, butterfly over rg
            float q0 = Tp2[0][0] * u2[0];
            q0 = fmaf(Tp2[1][0], u2[1], q0);
            q0 = fmaf(Tp2[2][0], u2[2], q0);
            q0 = fmaf(Tp2[3][0], u2[3], q0);
            float q1 = Tp2[0][1] * u2[0];
            q1 = fmaf(Tp2[1][1], u2[1], q1);
            q1 = fmaf(Tp2[2][1], u2[2], q1);
            q1 = fmaf(Tp2[3][1], u2[3], q1);
            float q2 = Tp2[0][2] * u2[0];
            q2 = fmaf(Tp2[1][2], u2[1], q2);
            q2 = fmaf(Tp2[2][2], u2[2], q2);
            q2 = fmaf(Tp2[3][2], u2[3], q2);
            sumq3(q0, q1, q2);
            vv0 = FRCP(fmaf(eK0u[0], u0_, q0));
            vv1 = FRCP(fmaf(eK0u[1], u0_, q1));
            vv2 = FRCP(fmaf(eK0cc2, u0_, q2));
        }

        // eK -> Tp: Tp = PWQP * u~ * eK * vv~  (scales cancel exactly)
        float puA = PWQP * u2[0], puB = PWQP * u2[1];
        float puC = PWQP * u2[2], puD = PWQP * u2[3];
        float pu0 = PWQP * u0_;
        Tp2[0][0] = (Tp2[0][0] * vv0) * puA;
        Tp2[0][1] = (Tp2[0][1] * vv1) * puA;
        Tp2[0][2] = (Tp2[0][2] * vv2) * puA;
        Tp2[1][0] = (Tp2[1][0] * vv0) * puB;
        Tp2[1][1] = (Tp2[1][1] * vv1) * puB;
        Tp2[1][2] = (Tp2[1][2] * vv2) * puB;
        Tp2[2][0] = (Tp2[2][0] * vv0) * puC;
        Tp2[2][1] = (Tp2[2][1] * vv1) * puC;
        Tp2[2][2] = (Tp2[2][2] * vv2) * puC;
        Tp2[3][0] = (Tp2[3][0] * vv0) * puD;
        Tp2[3][1] = (Tp2[3][1] * vv1) * puD;
        Tp2[3][2] = (Tp2[3][2] * vv2) * puD;
        TK0l[0] = (eK0u[0] * vv0) * pu0;
        TK0l[1] = (eK0u[1] * vv1) * pu0;
        TK0l[2] = (eK0u[2] * vv2) * pu0;
    }

    // ---- final objective
    {
        float s0 = ((Tp2[0][0] + Tp2[1][0]) + (Tp2[2][0] + Tp2[3][0]));
        float s1 = ((Tp2[0][1] + Tp2[1][1]) + (Tp2[2][1] + Tp2[3][1]));
        float s2 = ((Tp2[0][2] + Tp2[1][2]) + (Tp2[2][2] + Tp2[3][2]));
        sumq3(s0, s1, s2);
        s0 += TK0l[0]; s1 += TK0l[1]; s2 += TK0l[2];
        float sa0 = __shfl(s0, gbase + 0, 64),  ta0 = __shfl(TK0l[0], gbase + 0, 64);
        float sa1 = __shfl(s1, gbase + 0, 64),  ta1 = __shfl(TK0l[1], gbase + 0, 64);
        float sa2 = __shfl(s2, gbase + 0, 64),  ta2 = __shfl(TK0l[2], gbase + 0, 64);
        float sa3 = __shfl(s0, gbase + 4, 64),  ta3 = __shfl(TK0l[0], gbase + 4, 64);
        float sa4 = __shfl(s1, gbase + 4, 64),  ta4 = __shfl(TK0l[1], gbase + 4, 64);
        float sa5 = __shfl(s2, gbase + 4, 64),  ta5 = __shfl(TK0l[2], gbase + 4, 64);
        float sa6 = __shfl(s0, gbase + 8, 64),  ta6 = __shfl(TK0l[0], gbase + 8, 64);
        float sa7 = __shfl(s1, gbase + 8, 64),  ta7 = __shfl(TK0l[1], gbase + 8, 64);
        float sa8 = __shfl(s0, gbase + 12, 64), ta8 = __shfl(TK0l[0], gbase + 12, 64);
        float sa9 = __shfl(s1, gbase + 12, 64), ta9 = __shfl(TK0l[1], gbase + 12, 64);
        v2f r0 = *(const v2f*)(ctp);
        v2f r1 = *(const v2f*)(ctp + 2);
        v2f r2 = *(const v2f*)(ctp + 4);
        v2f r3 = *(const v2f*)(ctp + 6);
        v2f r4 = *(const v2f*)(ctp + 8);
        float Cs, C0;
        {
            float a = r0.x * sa0,   b = r0.y * sa1;
            a = fmaf(r1.x, sa2, a); b = fmaf(r1.y, sa3, b);
            a = fmaf(r2.x, sa4, a); b = fmaf(r2.y, sa5, b);
            a = fmaf(r3.x, sa6, a); b = fmaf(r3.y, sa7, b);
            a = fmaf(r4.x, sa8, a); b = fmaf(r4.y, sa9, b);
            Cs = a + b;
            float q = r0.x * ta0,   d = r0.y * ta1;
            q = fmaf(r1.x, ta2, q); d = fmaf(r1.y, ta3, d);
            q = fmaf(r2.x, ta4, q); d = fmaf(r2.y, ta5, d);
            q = fmaf(r3.x, ta6, q); d = fmaf(r3.y, ta7, d);
            q = fmaf(r4.x, ta8, q); d = fmaf(r4.y, ta9, d);
            C0 = q + d;
        }
        float g0l = (16.f / 17.f) + ct2q - 2.f * Cs;
        float g1l = (1.f  / 17.f) + ct2q - 2.f * C0;
        float G1_0 = __shfl(g1l, gbase + cbase + 0, 64);
        float G1_1 = __shfl(g1l, gbase + cbase + 1, 64);
        float G1_2 = __shfl(g1l, gbase + cbase + 2, 64);
        float G0_0 = __shfl(g0l, gbase + cbase + 0, 64);
        float G0_1 = __shfl(g0l, gbase + cbase + 1, 64);
        float G0_2 = __shfl(g0l, gbase + cbase + 2, 64);

        float objp = 0.f;
#pragma unroll
        for (int i2 = 0; i2 < 4; ++i2) {
            const int jb = obase + (1 + rg + 4 * i2) * EMS + cbase;
            objp += Tp2[i2][0] * (-EPSLN2 * FLOG2(sEM[jb])       + 0.5f * G1_0);
            objp += Tp2[i2][1] * (-EPSLN2 * FLOG2(sEM[jb + 1])   + 0.5f * G1_1);
            objp += Tp2[i2][2] * (-EPSLN2 * FLOG2(sEM[jb + c2o]) + 0.5f * G1_2);
        }
        float obj0p = TK0l[0] * (-EPSLN2 * FLOG2(sEM[obase + cbase])       + 0.5f * G0_0);
        obj0p      += TK0l[1] * (-EPSLN2 * FLOG2(sEM[obase + cbase + 1])   + 0.5f * G0_1);
        obj0p      += TK0l[2] * (-EPSLN2 * FLOG2(sEM[obase + cbase + c2o]) + 0.5f * G0_2);
        float tot = objp + ((rg == 0) ? obj0p : 0.f);
        float obj = sum16(tot);
        if (l == 0 && node < N) out[node * TT + t] = obj;
    }
}

extern "C" void kernel_launch(void* const* d_in, const int* in_sizes, int n_in,
                              void* d_out, int out_size, void* d_ws, size_t ws_size,
                              hipStream_t stream) {
    const float* x    = (const float*)d_in[0];
    const int*   ei   = (const int*)d_in[1];
    const float* tmpl = (const float*)d_in[2];
    const float* tf   = (const float*)d_in[3];
    float* out = (float*)d_out;
    int N = in_sizes[0] / DD;
    int gxb = (N + SLOTS - 1) / SLOTS;      // node-range blocks
    int mx  = (gxb + 7) / 8;                // node-ranges per XCD
    int grid = 8 * mx * TT;                 // XCD-swizzled 1D grid
    hipLaunchKernelGGL(ltfgw_kernel, dim3(grid), dim3(THREADS), 0, stream,
                       x, ei, tmpl, tf, out, N);
}

// Round 14
// 274.273 us; speedup vs baseline: 1.8227x; 1.0204x over previous
//
#include <hip/hip_runtime.h>

#define DEG 16
#define DD  128
#define KT  10      // template nodes (K)
#define TT  10      // templates
#define MM  17      // m = DEG+1
#define SLOTS 16    // node-slots per block (4 waves x 4 groups)
#define THREADS 256 // 4 independent waves
#define EMS 11      // eM overlay row stride

#if __has_builtin(__builtin_amdgcn_exp2f)
#define FEXP2(x) __builtin_amdgcn_exp2f(x)
#else
#define FEXP2(x) exp2f(x)
#endif

#if __has_builtin(__builtin_amdgcn_rcpf)
#define FRCP(x) __builtin_amdgcn_rcpf(x)
#else
#define FRCP(x) (1.0f / (x))
#endif

#if __has_builtin(__builtin_amdgcn_logf)
#define FLOG2(x) __builtin_amdgcn_logf(x)
#else
#define FLOG2(x) __log2f(x)
#endif

// (1/EPS)*log2(e), EPS = 0.5
#define TWO_LOG2E 2.8853900817779268f
#define NLOG2E    1.4426950408889634f
#define EPSLN2    0.34657359027997264f
// pw*QP = 1/10 exactly. Scale-invariant inner loop: the scale cancels
// exactly in the u*vv product that forms Tp.
#define PWQP      0.1f

typedef float v2f __attribute__((ext_vector_type(2)));
typedef float v4f __attribute__((ext_vector_type(4)));

// NOTE (R12 lesson): v_pk_*_f32 requires 64-bit register-PAIR operands in
// every source slot; op_sel_hi cannot widen a single VGPR scalar.
__device__ __forceinline__ v2f pk_fma(v2f a, v2f b, v2f c) {
    asm("v_pk_fma_f32 %0, %1, %2, %0" : "+v"(c) : "v"(a), "v"(b));
    return c;
}
__device__ __forceinline__ v2f pk_fma_s(v2f a, v2f bs, v2f c) {
    asm("v_pk_fma_f32 %0, %1, %2, %0" : "+v"(c) : "v"(a), "s"(bs));
    return c;
}

template <int CTRL>
__device__ __forceinline__ float dpp_add(float x) {
    union { float f; int i; } a, b;
    a.f = x;
    b.i = __builtin_amdgcn_update_dpp(0, a.i, CTRL, 0xF, 0xF, true);
    return x + b.f;
}
__device__ __forceinline__ float sum16(float t) {
    t = dpp_add<0xB1>(t);
    t = dpp_add<0x4E>(t);
    t = dpp_add<0x124>(t);
    t = dpp_add<0x128>(t);
    return t;
}

#define _D(i, CTRL) "v_add_f32_dpp %" #i ", %" #i ", %" #i " " CTRL \
                    " row_mask:0xf bank_mask:0xf bound_ctrl:0\n\t"
#define _C1 "quad_perm:[1,0,3,2]"
#define _C2 "quad_perm:[2,3,0,1]"
#define _C3 "row_ror:4"
#define _C4 "row_ror:8"

__device__ __forceinline__ void sum16x5(float& a0, float& a1, float& a2,
                                        float& a3, float& a4) {
    asm("s_nop 1\n\t"
        _D(0,_C1) _D(1,_C1) _D(2,_C1) _D(3,_C1) _D(4,_C1)
        _D(0,_C2) _D(1,_C2) _D(2,_C2) _D(3,_C2) _D(4,_C2)
        _D(0,_C3) _D(1,_C3) _D(2,_C3) _D(3,_C3) _D(4,_C3)
        _D(0,_C4) _D(1,_C4) _D(2,_C4) _D(3,_C4) _D(4,_C4)
        : "+v"(a0), "+v"(a1), "+v"(a2), "+v"(a3), "+v"(a4));
}
__device__ __forceinline__ void sum16x6(float& a0, float& a1, float& a2,
                                        float& a3, float& a4, float& a5) {
    asm("s_nop 1\n\t"
        _D(0,_C1) _D(1,_C1) _D(2,_C1) _D(3,_C1) _D(4,_C1) _D(5,_C1)
        _D(0,_C2) _D(1,_C2) _D(2,_C2) _D(3,_C2) _D(4,_C2) _D(5,_C2)
        _D(0,_C3) _D(1,_C3) _D(2,_C3) _D(3,_C3) _D(4,_C3) _D(5,_C3)
        _D(0,_C4) _D(1,_C4) _D(2,_C4) _D(3,_C4) _D(4,_C4) _D(5,_C4)
        : "+v"(a0), "+v"(a1), "+v"(a2), "+v"(a3), "+v"(a4), "+v"(a5));
}
__device__ __forceinline__ void sumq3(float& a0, float& a1, float& a2) {
    asm("s_nop 1\n\t"
        _D(0,_C1) _D(1,_C1) _D(2,_C1)
        "s_nop 0\n\t"
        _D(0,_C2) _D(1,_C2) _D(2,_C2)
        : "+v"(a0), "+v"(a1), "+v"(a2));
}
__device__ __forceinline__ void sums5(float& a0, float& a1, float& a2,
                                      float& a3, float& a4) {
    asm("s_nop 1\n\t"
        _D(0,_C3) _D(1,_C3) _D(2,_C3) _D(3,_C3) _D(4,_C3)
        _D(0,_C4) _D(1,_C4) _D(2,_C4) _D(3,_C4) _D(4,_C4)
        : "+v"(a0), "+v"(a1), "+v"(a2), "+v"(a3), "+v"(a4));
}

// R14 = R13 + (i) hard VGPR cap 64 (amdgpu_num_vgpr: the DIRECT knob --
// waves_per_eu / launch_bounds min-occ hints both collapsed to 32+spills
// in R3-R5) to recover the 8th wave/SIMD lost when R13 hit 68 VGPR, and
// (ii) Cs/C0 broadcast blocks split in two so only 10 shfl results are
// live at once instead of 20 (helps the allocator fit 64).
__global__ __launch_bounds__(THREADS)
__attribute__((amdgpu_num_vgpr(64)))
void ltfgw_kernel(
    const float* __restrict__ x,      // [N,128]
    const int*   __restrict__ ei,     // edge_index[0], [N*DEG]
    const float* __restrict__ tmpl,   // [T,K,K]
    const float* __restrict__ tf,     // [T,K,128]
    float* __restrict__ out,          // [N,T]
    int N)
{
    __shared__ float sEM[SLOTS * MM * EMS];   // 11968 B

    const int tid  = threadIdx.x;
    // XCD-swizzle decode (VERIFIED R13: FETCH 98MB->19MB): phys%8 = XCD;
    // k=phys>>3 enumerates (template fastest, then node-range).
    const int phys = blockIdx.x;
    const int xcd  = phys & 7;
    const int k    = phys >> 3;
    const int t    = k % TT;
    const int bx   = xcd + 8 * (k / TT);

    const int slot = tid >> 4;
    const int lane = tid & 63;
    const int l    = lane & 15;
    const int gbase = lane & ~15;
    const int node  = bx * SLOTS + slot;
    const int nodeC = (node < N) ? node : (N - 1);

    const int cl = (l < KT) ? l : 0;
    const float* ctp = tmpl + ((size_t)t * KT + cl) * KT;
    const float* tw  = tf + (size_t)t * KT * DD;

    // ---- ct2q = (Ct^2 @ q)[cl]
    float ct2q;
    {
        v2f r0 = *(const v2f*)(ctp);
        v2f r1 = *(const v2f*)(ctp + 2);
        v2f r2 = *(const v2f*)(ctp + 4);
        v2f r3 = *(const v2f*)(ctp + 6);
        v2f r4 = *(const v2f*)(ctp + 8);
        v2f acc = pk_fma(r0, r0, (v2f){0.f, 0.f});
        acc = pk_fma(r1, r1, acc);
        acc = pk_fma(r2, r2, acc);
        acc = pk_fma(r3, r3, acc);
        acc = pk_fma(r4, r4, acc);
        ct2q = (acc.x + acc.y) * (1.f / KT);
    }

    // ---- M main pass: own neighbor row from GLOBAL (L2-resident) vs
    // 10 template rows (wave-uniform -> SGPR operands)
    const int   srcl  = ei[nodeC * DEG + l];
    const float* myrow = x + (size_t)srcl * DD;
    v2f dotv[KT];
#pragma unroll
    for (int c = 0; c < KT; ++c) dotv[c] = (v2f){0.f, 0.f};
    v2f nrmv = (v2f){0.f, 0.f};
#pragma unroll 4
    for (int kk4 = 0; kk4 < 32; ++kk4) {
        v4f a4 = *(const v4f*)(myrow + kk4 * 4);
        nrmv = pk_fma(a4.lo, a4.lo, nrmv);
        nrmv = pk_fma(a4.hi, a4.hi, nrmv);
#pragma unroll
        for (int c = 0; c < KT; ++c) {
            v4f f4 = *(const v4f*)(tw + c * DD + kk4 * 4);   // s_load
            dotv[c] = pk_fma_s(a4.lo, f4.lo, dotv[c]);
            dotv[c] = pk_fma_s(a4.hi, f4.hi, dotv[c]);
        }
    }
    float nrm_own = nrmv.x + nrmv.y;

    // ---- mini-pass: center row (global, coalesced) + template norms
    float dot0[KT], nft[KT], n0p;
    {
        const float* row0 = x + (size_t)nodeC * DD + 8 * l;
        v4f z0 = *(const v4f*)(row0);
        v4f z1 = *(const v4f*)(row0 + 4);
        v2f nn = pk_fma(z0.lo, z0.lo, (v2f){0.f, 0.f});
        nn = pk_fma(z0.hi, z0.hi, nn);
        nn = pk_fma(z1.lo, z1.lo, nn);
        nn = pk_fma(z1.hi, z1.hi, nn);
        n0p = nn.x + nn.y;
#pragma unroll
        for (int c = 0; c < KT; ++c) {
            const float* tr = tw + c * DD + 8 * l;
            v4f t0_ = *(const v4f*)(tr);
            v4f t1_ = *(const v4f*)(tr + 4);
            v2f d = pk_fma(z0.lo, t0_.lo, (v2f){0.f, 0.f});
            d = pk_fma(z0.hi, t0_.hi, d);
            d = pk_fma(z1.lo, t1_.lo, d);
            d = pk_fma(z1.hi, t1_.hi, d);
            dot0[c] = d.x + d.y;
            v2f nf = pk_fma(t0_.lo, t0_.lo, (v2f){0.f, 0.f});
            nf = pk_fma(t0_.hi, t0_.hi, nf);
            nf = pk_fma(t1_.lo, t1_.lo, nf);
            nf = pk_fma(t1_.hi, t1_.hi, nf);
            nft[c] = nf.x + nf.y;
        }
        sum16x6(dot0[0], dot0[1], dot0[2], dot0[3], dot0[4], dot0[5]);
        sum16x5(dot0[6], dot0[7], dot0[8], dot0[9], n0p);
        sum16x5(nft[0], nft[1], nft[2], nft[3], nft[4]);
        sum16x5(nft[5], nft[6], nft[7], nft[8], nft[9]);
    }

    // ---- eM factors -> LDS overlay (same-wave traffic, lgkm-ordered)
    const int obase = slot * (MM * EMS);
    {
        const int rb = obase + (l + 1) * EMS;
#pragma unroll
        for (int c = 0; c < KT; c += 2) {
            float eA = FEXP2(-NLOG2E * ((nrm_own + nft[c] - 2.f * (dotv[c].x + dotv[c].y)) * (1.f / DD)));
            float eB = FEXP2(-NLOG2E * ((nrm_own + nft[c + 1] - 2.f * (dotv[c + 1].x + dotv[c + 1].y)) * (1.f / DD)));
            *(v2f*)(&sEM[rb + c]) = (v2f){eA, eB};
        }
        if (l == 0) {
#pragma unroll
            for (int c = 0; c < KT; c += 2) {
                float eA = FEXP2(-NLOG2E * ((n0p + nft[c] - 2.f * dot0[c]) * (1.f / DD)));
                float eB = FEXP2(-NLOG2E * ((n0p + nft[c + 1] - 2.f * dot0[c + 1]) * (1.f / DD)));
                *(v2f*)(&sEM[obase + c]) = (v2f){eA, eB};
            }
        }
    }

    // ---- 2D roles
    const int rg = l & 3, cg = l >> 2;
    const int cbase = 2 * cg + (cg < 2 ? cg : 2);   // 0,3,6,8
    const bool isd = (cg >= 2);
    const int c2o = isd ? 0 : 2;

    float Tp2[4][3], TK0l[3];
    float vv0, vv1, vv2;
#pragma unroll
    for (int i2 = 0; i2 < 4; ++i2) {
        Tp2[i2][0] = 1.f / (MM * KT);
        Tp2[i2][1] = 1.f / (MM * KT);
        Tp2[i2][2] = isd ? 0.f : (1.f / (MM * KT));
    }
    TK0l[0] = 1.f / (MM * KT);
    TK0l[1] = 1.f / (MM * KT);
    TK0l[2] = isd ? 0.f : (1.f / (MM * KT));
    float u2[4] = {0.f, 0.f, 0.f, 0.f}, u0_ = 0.f;
    float eK0u[3] = {0.f, 0.f, 0.f};

#pragma unroll 1
    for (int outer = 0; outer < 5; ++outer) {
        // col-sums of Tp (quad butterfly over rg) + row0 term
        float s0 = ((Tp2[0][0] + Tp2[1][0]) + (Tp2[2][0] + Tp2[3][0]));
        float s1 = ((Tp2[0][1] + Tp2[1][1]) + (Tp2[2][1] + Tp2[3][1]));
        float s2 = ((Tp2[0][2] + Tp2[1][2]) + (Tp2[2][2] + Tp2[3][2]));
        sumq3(s0, s1, s2);
        s0 += TK0l[0]; s1 += TK0l[1]; s2 += TK0l[2];

        v2f r0 = *(const v2f*)(ctp);
        v2f r1 = *(const v2f*)(ctp + 2);
        v2f r2 = *(const v2f*)(ctp + 4);
        v2f r3 = *(const v2f*)(ctp + 6);
        v2f r4 = *(const v2f*)(ctp + 8);
        float Cs, C0;
        {   // s-broadcasts only (10 live temps, not 20)
            float b0 = __shfl(s0, gbase + 0, 64);
            float b1 = __shfl(s1, gbase + 0, 64);
            float b2 = __shfl(s2, gbase + 0, 64);
            float b3 = __shfl(s0, gbase + 4, 64);
            float b4 = __shfl(s1, gbase + 4, 64);
            float b5 = __shfl(s2, gbase + 4, 64);
            float b6 = __shfl(s0, gbase + 8, 64);
            float b7 = __shfl(s1, gbase + 8, 64);
            float b8 = __shfl(s0, gbase + 12, 64);
            float b9 = __shfl(s1, gbase + 12, 64);
            float a = r0.x * b0,    b = r0.y * b1;
            a = fmaf(r1.x, b2, a);  b = fmaf(r1.y, b3, b);
            a = fmaf(r2.x, b4, a);  b = fmaf(r2.y, b5, b);
            a = fmaf(r3.x, b6, a);  b = fmaf(r3.y, b7, b);
            a = fmaf(r4.x, b8, a);  b = fmaf(r4.y, b9, b);
            Cs = a + b;
        }
        {   // TK0-broadcasts only
            float b0 = __shfl(TK0l[0], gbase + 0, 64);
            float b1 = __shfl(TK0l[1], gbase + 0, 64);
            float b2 = __shfl(TK0l[2], gbase + 0, 64);
            float b3 = __shfl(TK0l[0], gbase + 4, 64);
            float b4 = __shfl(TK0l[1], gbase + 4, 64);
            float b5 = __shfl(TK0l[2], gbase + 4, 64);
            float b6 = __shfl(TK0l[0], gbase + 8, 64);
            float b7 = __shfl(TK0l[1], gbase + 8, 64);
            float b8 = __shfl(TK0l[0], gbase + 12, 64);
            float b9 = __shfl(TK0l[1], gbase + 12, 64);
            float q = r0.x * b0,    d = r0.y * b1;
            q = fmaf(r1.x, b2, q);  d = fmaf(r1.y, b3, d);
            q = fmaf(r2.x, b4, q);  d = fmaf(r2.y, b5, d);
            q = fmaf(r3.x, b6, q);  d = fmaf(r3.y, b7, d);
            q = fmaf(r4.x, b8, q);  d = fmaf(r4.y, b9, d);
            C0 = q + d;
        }
        float e0 = FEXP2(-TWO_LOG2E * ((16.f / 17.f) + ct2q - 2.f * Cs));
        float e1 = FEXP2(-TWO_LOG2E * ((1.f  / 17.f) + ct2q - 2.f * C0));

        float E1_0 = __shfl(e1, gbase + cbase + 0, 64);
        float E1_1 = __shfl(e1, gbase + cbase + 1, 64);
        float E1_2 = __shfl(e1, gbase + cbase + 2, 64);
        float E0_0 = __shfl(e0, gbase + cbase + 0, 64);
        float E0_1 = __shfl(e0, gbase + cbase + 1, 64);
        float E0_2 = __shfl(e0, gbase + cbase + 2, 64);

        // mirror: Tp -> eK in place (eM streamed from LDS)
#pragma unroll
        for (int i2 = 0; i2 < 4; ++i2) {
            const int jb = obase + (1 + rg + 4 * i2) * EMS + cbase;
            Tp2[i2][0] *= sEM[jb]       * E1_0;
            Tp2[i2][1] *= sEM[jb + 1]   * E1_1;
            Tp2[i2][2] *= sEM[jb + c2o] * E1_2;   // dummy: 0 * finite = 0
        }
        eK0u[0] = TK0l[0] * (sEM[obase + cbase]       * E0_0);
        eK0u[1] = TK0l[1] * (sEM[obase + cbase + 1]   * E0_1);
        eK0u[2] = TK0l[2] * (sEM[obase + cbase + c2o] * E0_2);
        float eK0cc2 = isd ? 1.f : eK0u[2];   // keeps dummy colacc > 0
        // scale-invariant domain: vv starts at 1; no RQP anywhere inside.
        vv0 = 1.f; vv1 = 1.f; vv2 = 1.f;

#pragma unroll 1
        for (int it = 0; it < 10; ++it) {
            // u-update: row partials over my 3 cols, butterfly over cg
            float p0 = Tp2[0][0] * vv0;
            p0 = fmaf(Tp2[0][1], vv1, p0); p0 = fmaf(Tp2[0][2], vv2, p0);
            float p1 = Tp2[1][0] * vv0;
            p1 = fmaf(Tp2[1][1], vv1, p1); p1 = fmaf(Tp2[1][2], vv2, p1);
            float p2 = Tp2[2][0] * vv0;
            p2 = fmaf(Tp2[2][1], vv1, p2); p2 = fmaf(Tp2[2][2], vv2, p2);
            float p3 = Tp2[3][0] * vv0;
            p3 = fmaf(Tp2[3][1], vv1, p3); p3 = fmaf(Tp2[3][2], vv2, p3);
            float p4 = eK0u[0] * vv0;
            p4 = fmaf(eK0u[1], vv1, p4); p4 = fmaf(eK0u[2], vv2, p4);
            sums5(p0, p1, p2, p3, p4);
            u2[0] = FRCP(p0);
            u2[1] = FRCP(p1);
            u2[2] = FRCP(p2);
            u2[3] = FRCP(p3);
            u0_   = FRCP(p4);
            // v-update: col partials over my 4 rows, butterfly over rg
            float q0 = Tp2[0][0] * u2[0];
            q0 = fmaf(Tp2[1][0], u2[1], q0);
            q0 = fmaf(Tp2[2][0], u2[2], q0);
            q0 = fmaf(Tp2[3][0], u2[3], q0);
            float q1 = Tp2[0][1] * u2[0];
            q1 = fmaf(Tp2[1][1], u2[1], q1);
            q1 = fmaf(Tp2[2][1], u2[2], q1);
            q1 = fmaf(Tp2[3][1], u2[3], q1);
            float q2 = Tp2[0][2] * u2[0];
            q2 = fmaf(Tp2[1][2], u2[1], q2);
            q2 = fmaf(Tp2[2][2], u2[2], q2);
            q2 = fmaf(Tp2[3][2], u2[3], q2);
            sumq3(q0, q1, q2);
            vv0 = FRCP(fmaf(eK0u[0], u0_, q0));
            vv1 = FRCP(fmaf(eK0u[1], u0_, q1));
            vv2 = FRCP(fmaf(eK0cc2, u0_, q2));
        }

        // eK -> Tp: Tp = PWQP * u~ * eK * vv~  (scales cancel exactly)
        float puA = PWQP * u2[0], puB = PWQP * u2[1];
        float puC = PWQP * u2[2], puD = PWQP * u2[3];
        float pu0 = PWQP * u0_;
        Tp2[0][0] = (Tp2[0][0] * vv0) * puA;
        Tp2[0][1] = (Tp2[0][1] * vv1) * puA;
        Tp2[0][2] = (Tp2[0][2] * vv2) * puA;
        Tp2[1][0] = (Tp2[1][0] * vv0) * puB;
        Tp2[1][1] = (Tp2[1][1] * vv1) * puB;
        Tp2[1][2] = (Tp2[1][2] * vv2) * puB;
        Tp2[2][0] = (Tp2[2][0] * vv0) * puC;
        Tp2[2][1] = (Tp2[2][1] * vv1) * puC;
        Tp2[2][2] = (Tp2[2][2] * vv2) * puC;
        Tp2[3][0] = (Tp2[3][0] * vv0) * puD;
        Tp2[3][1] = (Tp2[3][1] * vv1) * puD;
        Tp2[3][2] = (Tp2[3][2] * vv2) * puD;
        TK0l[0] = (eK0u[0] * vv0) * pu0;
        TK0l[1] = (eK0u[1] * vv1) * pu0;
        TK0l[2] = (eK0u[2] * vv2) * pu0;
    }

    // ---- final objective
    {
        float s0 = ((Tp2[0][0] + Tp2[1][0]) + (Tp2[2][0] + Tp2[3][0]));
        float s1 = ((Tp2[0][1] + Tp2[1][1]) + (Tp2[2][1] + Tp2[3][1]));
        float s2 = ((Tp2[0][2] + Tp2[1][2]) + (Tp2[2][2] + Tp2[3][2]));
        sumq3(s0, s1, s2);
        s0 += TK0l[0]; s1 += TK0l[1]; s2 += TK0l[2];

        v2f r0 = *(const v2f*)(ctp);
        v2f r1 = *(const v2f*)(ctp + 2);
        v2f r2 = *(const v2f*)(ctp + 4);
        v2f r3 = *(const v2f*)(ctp + 6);
        v2f r4 = *(const v2f*)(ctp + 8);
        float Cs, C0;
        {
            float b0 = __shfl(s0, gbase + 0, 64);
            float b1 = __shfl(s1, gbase + 0, 64);
            float b2 = __shfl(s2, gbase + 0, 64);
            float b3 = __shfl(s0, gbase + 4, 64);
            float b4 = __shfl(s1, gbase + 4, 64);
            float b5 = __shfl(s2, gbase + 4, 64);
            float b6 = __shfl(s0, gbase + 8, 64);
            float b7 = __shfl(s1, gbase + 8, 64);
            float b8 = __shfl(s0, gbase + 12, 64);
            float b9 = __shfl(s1, gbase + 12, 64);
            float a = r0.x * b0,    b = r0.y * b1;
            a = fmaf(r1.x, b2, a);  b = fmaf(r1.y, b3, b);
            a = fmaf(r2.x, b4, a);  b = fmaf(r2.y, b5, b);
            a = fmaf(r3.x, b6, a);  b = fmaf(r3.y, b7, b);
            a = fmaf(r4.x, b8, a);  b = fmaf(r4.y, b9, b);
            Cs = a + b;
        }
        {
            float b0 = __shfl(TK0l[0], gbase + 0, 64);
            float b1 = __shfl(TK0l[1], gbase + 0, 64);
            float b2 = __shfl(TK0l[2], gbase + 0, 64);
            float b3 = __shfl(TK0l[0], gbase + 4, 64);
            float b4 = __shfl(TK0l[1], gbase + 4, 64);
            float b5 = __shfl(TK0l[2], gbase + 4, 64);
            float b6 = __shfl(TK0l[0], gbase + 8, 64);
            float b7 = __shfl(TK0l[1], gbase + 8, 64);
            float b8 = __shfl(TK0l[0], gbase + 12, 64);
            float b9 = __shfl(TK0l[1], gbase + 12, 64);
            float q = r0.x * b0,    d = r0.y * b1;
            q = fmaf(r1.x, b2, q);  d = fmaf(r1.y, b3, d);
            q = fmaf(r2.x, b4, q);  d = fmaf(r2.y, b5, d);
            q = fmaf(r3.x, b6, q);  d = fmaf(r3.y, b7, d);
            q = fmaf(r4.x, b8, q);  d = fmaf(r4.y, b9, d);
            C0 = q + d;
        }
        float g0l = (16.f / 17.f) + ct2q - 2.f * Cs;
        float g1l = (1.f  / 17.f) + ct2q - 2.f * C0;
        float G1_0 = __shfl(g1l, gbase + cbase + 0, 64);
        float G1_1 = __shfl(g1l, gbase + cbase + 1, 64);
        float G1_2 = __shfl(g1l, gbase + cbase + 2, 64);
        float G0_0 = __shfl(g0l, gbase + cbase + 0, 64);
        float G0_1 = __shfl(g0l, gbase + cbase + 1, 64);
        float G0_2 = __shfl(g0l, gbase + cbase + 2, 64);

        float objp = 0.f;
#pragma unroll
        for (int i2 = 0; i2 < 4; ++i2) {
            const int jb = obase + (1 + rg + 4 * i2) * EMS + cbase;
            objp += Tp2[i2][0] * (-EPSLN2 * FLOG2(sEM[jb])       + 0.5f * G1_0);
            objp += Tp2[i2][1] * (-EPSLN2 * FLOG2(sEM[jb + 1])   + 0.5f * G1_1);
            objp += Tp2[i2][2] * (-EPSLN2 * FLOG2(sEM[jb + c2o]) + 0.5f * G1_2);
        }
        float obj0p = TK0l[0] * (-EPSLN2 * FLOG2(sEM[obase + cbase])       + 0.5f * G0_0);
        obj0p      += TK0l[1] * (-EPSLN2 * FLOG2(sEM[obase + cbase + 1])   + 0.5f * G0_1);
        obj0p      += TK0l[2] * (-EPSLN2 * FLOG2(sEM[obase + cbase + c2o]) + 0.5f * G0_2);
        float tot = objp + ((rg == 0) ? obj0p : 0.f);
        float obj = sum16(tot);
        if (l == 0 && node < N) out[node * TT + t] = obj;
    }
}

extern "C" void kernel_launch(void* const* d_in, const int* in_sizes, int n_in,
                              void* d_out, int out_size, void* d_ws, size_t ws_size,
                              hipStream_t stream) {
    const float* x    = (const float*)d_in[0];
    const int*   ei   = (const int*)d_in[1];
    const float* tmpl = (const float*)d_in[2];
    const float* tf   = (const float*)d_in[3];
    float* out = (float*)d_out;
    int N = in_sizes[0] / DD;
    int gxb = (N + SLOTS - 1) / SLOTS;      // node-range blocks
    int mx  = (gxb + 7) / 8;                // node-ranges per XCD
    int grid = 8 * mx * TT;                 // XCD-swizzled 1D grid
    hipLaunchKernelGGL(ltfgw_kernel, dim3(grid), dim3(THREADS), 0, stream,
                       x, ei, tmpl, tf, out, N);
}